// Round 5
// baseline (15571.336 us; speedup 1.0000x reference)
//
#include <hip/hip_runtime.h>
#include <hip/hip_bf16.h>

#define NWG   128
#define NTHR  1024
#define HQ    512

typedef __attribute__((ext_vector_type(8))) short bf16x8;
typedef __attribute__((ext_vector_type(4))) float f32x4;
typedef unsigned short u16;

__device__ __forceinline__ float sigm(float x){ return 1.f/(1.f+__expf(-x)); }
__device__ __forceinline__ float tanhf_(float x){ return 1.f - 2.f/(1.f+__expf(2.f*x)); }
__device__ __forceinline__ u16 f2bf(float x){
  union { float f; unsigned u; } v; v.f = x;
  return (u16)((v.u + 0x7fffu + ((v.u >> 16) & 1u)) >> 16);
}

// Grid barrier (cached-data + fence protocol, R3-proven):
// release fence (wbl2) by tid0 before arrival flag; all WGs poll all flags;
// after the post-poll __syncthreads every producer's wbl2 is complete, so the
// all-thread acquire fence (L1+L2 inv) cannot race any in-flight writeback.
__device__ __forceinline__ void gridbar(unsigned* bar, unsigned barno, int wg){
  __syncthreads();
  if (threadIdx.x == 0){
    __builtin_amdgcn_fence(__ATOMIC_RELEASE, "agent");
    __hip_atomic_store(&bar[wg*16], barno, __ATOMIC_RELAXED, __HIP_MEMORY_SCOPE_AGENT);
  }
  if (threadIdx.x < NWG){
    unsigned* f = &bar[threadIdx.x*16];
    while (__hip_atomic_load(f, __ATOMIC_RELAXED, __HIP_MEMORY_SCOPE_AGENT) < barno)
      __builtin_amdgcn_s_sleep(2);
  }
  __syncthreads();
  __builtin_amdgcn_fence(__ATOMIC_ACQUIRE, "agent");
}

// One LSTM layer half-step for one wave: gates[16 batch rows x 16 gate rows]
// = [lo|hi](rows) @ Wslice^T + bias. Weights bw[32] live in registers.
__device__ __forceinline__ void lstm_half(
    const bf16x8 (&bw)[32],
    const u16* __restrict__ lo, const u16* __restrict__ hi,
    const float* __restrict__ sbias, u16* __restrict__ dst,
    float* cst, int wg, int mw, int lane)
{
  const int col = lane & 15, kg = lane >> 4;
  const int ao = (mw*16 + col) * HQ + kg*8;
  bf16x8 a[32];
  #pragma unroll
  for (int t = 0; t < 16; ++t) a[t]      = *(const bf16x8*)(lo + ao + t*32);
  #pragma unroll
  for (int t = 0; t < 16; ++t) a[16 + t] = *(const bf16x8*)(hi + ao + t*32);
  f32x4 ac0 = {0.f,0.f,0.f,0.f}, ac1 = {0.f,0.f,0.f,0.f};
  #pragma unroll
  for (int t = 0; t < 16; ++t){
    ac0 = __builtin_amdgcn_mfma_f32_16x16x32_bf16(a[2*t],   bw[2*t],   ac0, 0, 0, 0);
    ac1 = __builtin_amdgcn_mfma_f32_16x16x32_bf16(a[2*t+1], bw[2*t+1], ac1, 0, 0, 0);
  }
  f32x4 acc = ac0 + ac1;
  const int c4 = col & 3;
  #pragma unroll
  for (int r = 0; r < 4; ++r){
    float v  = acc[r];
    float vf = __shfl(v, (lane + 4) & 63);
    float vg = __shfl(v, (lane + 8) & 63);
    float vo = __shfl(v, (lane + 12) & 63);
    float vi = v + sbias[c4];              // garbage on col>=4 lanes, unused
    vf += sbias[4 + c4];
    vg += sbias[8 + c4];
    vo += sbias[12 + c4];
    float co = cst[r];
    float cn = sigm(vf)*co + sigm(vi)*tanhf_(vg);
    if (col < 4) cst[r] = cn;
    float hv = sigm(vo)*tanhf_(cn);
    if (col < 4)
      dst[(mw*16 + kg*4 + r)*HQ + wg*4 + col] = f2bf(hv);
  }
}

__global__ __launch_bounds__(NTHR) void lstm_ae_kernel(
  const float* __restrict__ initial_hidden,
  const float* __restrict__ Wih0, const float* __restrict__ Whh0,
  const float* __restrict__ bih0, const float* __restrict__ bhh0,
  const float* __restrict__ Wih1, const float* __restrict__ Whh1,
  const float* __restrict__ bih1, const float* __restrict__ bhh1,
  const float* __restrict__ Wlin, const float* __restrict__ blin,
  const int* __restrict__ seqp,
  float* __restrict__ dout, char* __restrict__ ws)
{
  __shared__ __align__(16) u16 w1s[16*1024];   // [Weff | Whh0] slice, 32 KB
  __shared__ __align__(16) u16 w2s[16*1024];   // [Wih1 | Whh1] slice, 32 KB
  __shared__ float s_b0[16], s_b1[16];
  __shared__ char pad_[20480];                 // force 1 WG/CU (total LDS > 80 KB)

  const int tid = threadIdx.x, wg = blockIdx.x;
  const int w = tid >> 6, lane = tid & 63;
  const int col = lane & 15, kg = lane >> 4;
  const int T = seqp[0];
  if (T < 0) pad_[0] = 1;                      // keep pad_ allocated

  unsigned* bar = (unsigned*)ws;               // 128 x 64B arrival lines
  u16* h0b[2];
  h0b[0] = (u16*)(ws + 8192);
  h0b[1] = h0b[0] + 65536;
  u16* wlinb = h0b[1] + 65536;                 // Wlin bf16 [256][512]
  u16* hist  = (u16*)dout;                     // h1 history: slot j = 65536 u16

  // ---------------- prologue ----------------
  // 1) stage this WG's 16 Wih0 rows (f32) into w2s-aliased scratch
  float* sw = (float*)w2s;                     // 16*256 f32 = 16 KB
  for (int it = tid; it < 16*256; it += NTHR){
    const int rr = it >> 8, d = it & 255;
    const int j = ((rr >> 2) & 3)*512 + wg*4 + (rr & 3);
    sw[it] = Wih0[j*256 + d];
  }
  __syncthreads();
  // 2) Weff = Wih0_slice @ Wlin -> w1s[rr][0..512), bf16
  {
    const int c = tid & 511, rr0 = (tid >> 9) * 8;
    float acc8[8];
    #pragma unroll
    for (int k = 0; k < 8; ++k) acc8[k] = 0.f;
    for (int d = 0; d < 256; ++d){
      const float wl = Wlin[d*512 + c];
      #pragma unroll
      for (int k = 0; k < 8; ++k) acc8[k] += sw[(rr0 + k)*256 + d] * wl;
    }
    #pragma unroll
    for (int k = 0; k < 8; ++k) w1s[(rr0 + k)*1024 + c] = f2bf(acc8[k]);
  }
  __syncthreads();
  // 3) biases (needs sw): b0eff = bih0+bhh0+Wih0@blin ; b1 = bih1+bhh1
  if (tid < 16){
    const int rr = tid;
    const int j = ((rr >> 2) & 3)*512 + wg*4 + (rr & 3);
    float s = bih0[j] + bhh0[j];
    for (int d = 0; d < 256; ++d) s += sw[rr*256 + d] * blin[d];
    s_b0[rr] = s;
  } else if (tid < 32){
    const int rr = tid - 16;
    const int j = ((rr >> 2) & 3)*512 + wg*4 + (rr & 3);
    s_b1[rr] = bih1[j] + bhh1[j];
  }
  __syncthreads();
  // 4) Whh0 -> w1s high half; W1 -> w2s (overwrites sw); wlinb; h inits
  for (int it = tid; it < 16*512; it += NTHR){
    const int rr = it >> 9, kk = it & 511;
    const int j = ((rr >> 2) & 3)*512 + wg*4 + (rr & 3);
    w1s[rr*1024 + 512 + kk] = f2bf(Whh0[j*512 + kk]);
  }
  __syncthreads();   // sw dead only after bias+Weff; keep ordering w.r.t. w2s
  for (int it = tid; it < 16*1024; it += NTHR){
    const int rr = it >> 10, e = it & 1023;
    const int j = ((rr >> 2) & 3)*512 + wg*4 + (rr & 3);
    const float v = (e < 512) ? Wih1[j*512 + e] : Whh1[j*512 + (e - 512)];
    w2s[rr*1024 + e] = f2bf(v);
  }
  {
    const int i = wg*1024 + tid;               // Wlin -> bf16, 1024 elems/WG
    wlinb[i] = f2bf(Wlin[i]);
  }
  if (tid < 512){
    const int i = wg*512 + tid;
    h0b[0][i] = f2bf(initial_hidden[65536 + i]);                 // h0 init
    hist[(size_t)(T - 1)*65536 + i] = f2bf(initial_hidden[i]);   // h1(0) -> slot T-1
  }
  __syncthreads();
  // 5) load this wave's weight slice into registers (static unroll -> VGPRs)
  bf16x8 bw[32];
  {
    const u16* wb = (w < 8) ? w1s : w2s;
    const int bo = col*1024 + kg*8;
    #pragma unroll
    for (int t = 0; t < 32; ++t) bw[t] = *(const bf16x8*)(wb + bo + t*32);
  }

  unsigned barno = 0;
  gridbar(bar, ++barno, wg);   // publish ws (wlinb, h0, hist slot T-1)

  float cst[4] = {0.f, 0.f, 0.f, 0.f};

  // ---------------- sequential loop ----------------
  int p = 0;
  for (int s = 1; s < T; ++s){
    const u16* h1p = hist + (size_t)(T - s)*65536;
    // phase 1: gates0 = h1_prev@Weff^T + h0_prev@Whh0^T -> h0_new (waves 0-7)
    if (w < 8)
      lstm_half(bw, h1p, h0b[p], s_b0, h0b[p ^ 1], cst, wg, w, lane);
    gridbar(bar, ++barno, wg);
    // phase 2: gates1 = h0_new@Wih1^T + h1_prev@Whh1^T -> h1_new (waves 8-15)
    if (w >= 8)
      lstm_half(bw, h0b[p ^ 1], h1p, s_b1,
                hist + (size_t)(T - 1 - s)*65536, cst, wg, w - 8, lane);
    gridbar(bar, ++barno, wg);
    p ^= 1;
  }

  // ---------------- output epilogue: out[j] = h1hist[j] @ Wlin^T + blin ----
  // One slot per 8-wave group; in-place over the bf16 history (per-lane
  // dataflow guarantees all reads complete before any write).
  for (int j = wg*2 + (w >> 3); j < T; j += 2*NWG){
    const u16* hsl = hist + (size_t)j*65536;
    float* osl = dout + (size_t)j*32768;
    const int mrow = (w & 7) * 16;
    bf16x8 a[16];
    #pragma unroll
    for (int t = 0; t < 16; ++t)
      a[t] = *(const bf16x8*)(hsl + (mrow + col)*HQ + t*32 + kg*8);
    #pragma unroll
    for (int nb = 0; nb < 16; ++nb){
      f32x4 acc = {0.f,0.f,0.f,0.f};
      #pragma unroll
      for (int t = 0; t < 16; ++t){
        bf16x8 b = *(const bf16x8*)(wlinb + (nb*16 + col)*HQ + t*32 + kg*8);
        acc = __builtin_amdgcn_mfma_f32_16x16x32_bf16(a[t], b, acc, 0, 0, 0);
      }
      const float bl = blin[nb*16 + col];
      #pragma unroll
      for (int r = 0; r < 4; ++r)
        osl[(mrow + kg*4 + r)*256 + nb*16 + col] = acc[r] + bl;
    }
  }
}

extern "C" void kernel_launch(void* const* d_in, const int* in_sizes, int n_in,
                              void* d_out, int out_size, void* d_ws, size_t ws_size,
                              hipStream_t stream) {
  const float* initial_hidden = (const float*)d_in[0];
  const float* Wih0 = (const float*)d_in[1];
  const float* Whh0 = (const float*)d_in[2];
  const float* bih0 = (const float*)d_in[3];
  const float* bhh0 = (const float*)d_in[4];
  const float* Wih1 = (const float*)d_in[5];
  const float* Whh1 = (const float*)d_in[6];
  const float* bih1 = (const float*)d_in[7];
  const float* bhh1 = (const float*)d_in[8];
  const float* Wlin = (const float*)d_in[9];
  const float* blin = (const float*)d_in[10];
  const int*   seqp = (const int*)d_in[11];

  hipMemsetAsync(d_ws, 0, 8192, stream);
  lstm_ae_kernel<<<dim3(NWG), dim3(NTHR), 0, stream>>>(
      initial_hidden, Wih0, Whh0, bih0, bhh0, Wih1, Whh1, bih1, bhh1,
      Wlin, blin, seqp, (float*)d_out, (char*)d_ws);
}

// Round 6
// 10473.138 us; speedup vs baseline: 1.4868x; 1.4868x over previous
//
#include <hip/hip_runtime.h>
#include <hip/hip_bf16.h>

#define NWG  128
#define NTHR 512

typedef __attribute__((ext_vector_type(8))) short bf16x8;
typedef __attribute__((ext_vector_type(4))) float f32x4;
typedef unsigned short u16;

__device__ __forceinline__ float sigm(float x){ return 1.f/(1.f+__expf(-x)); }
__device__ __forceinline__ float tanhf_(float x){ return 1.f - 2.f/(1.f+__expf(2.f*x)); }
__device__ __forceinline__ u16 f2bf(float x){
  union { float f; unsigned u; } v; v.f = x;
  return (u16)((v.u + 0x7fffu + ((v.u >> 16) & 1u)) >> 16);
}
// 8 consecutive f32 -> bf16x8 (works for global or LDS source)
__device__ __forceinline__ bf16x8 load8cvt(const float* p){
  f32x4 x0 = *(const f32x4*)p;
  f32x4 x1 = *(const f32x4*)(p + 4);
  union { u16 h[8]; bf16x8 v; } u;
  #pragma unroll
  for (int e = 0; e < 4; ++e){ u.h[e] = f2bf(x0[e]); u.h[4+e] = f2bf(x1[e]); }
  return u.v;
}

// Grid barrier (R3/R5-proven protocol): release fence by tid0 before its flag
// store; everyone polls all flags; acquire fence after reconvergence.
__device__ __forceinline__ void gridbar(unsigned* bar, unsigned barno, int wg){
  __syncthreads();
  if (threadIdx.x == 0){
    __builtin_amdgcn_fence(__ATOMIC_RELEASE, "agent");
    __hip_atomic_store(&bar[wg*16], barno, __ATOMIC_RELAXED, __HIP_MEMORY_SCOPE_AGENT);
  }
  if (threadIdx.x < NWG){
    unsigned* f = &bar[threadIdx.x*16];
    while (__hip_atomic_load(f, __ATOMIC_RELAXED, __HIP_MEMORY_SCOPE_AGENT) < barno)
      __builtin_amdgcn_s_sleep(2);
  }
  __syncthreads();
  __builtin_amdgcn_fence(__ATOMIC_ACQUIRE, "agent");
}

// acc{0,1} += A(rows pw*32..+32 of h, K=512) @ bw[HO..HO+16)^T
// HO is a compile-time half-offset so bw[] stays fully register-resident.
template<int HO>
__device__ __forceinline__ void gemm_half(const bf16x8 (&bw)[32], const u16* h,
    f32x4& acc0, f32x4& acc1, int pw, int lane)
{
  const int col = lane & 15, kg = lane >> 4;
  const u16* a0p = h + (pw*32 + col)*512 + kg*8;
  #pragma unroll
  for (int ks = 0; ks < 16; ++ks){
    bf16x8 a0 = *(const bf16x8*)(a0p + ks*32);
    bf16x8 a1 = *(const bf16x8*)(a0p + 16*512 + ks*32);
    acc0 = __builtin_amdgcn_mfma_f32_16x16x32_bf16(a0, bw[HO + ks], acc0, 0, 0, 0);
    acc1 = __builtin_amdgcn_mfma_f32_16x16x32_bf16(a1, bw[HO + ks], acc1, 0, 0, 0);
  }
}

// LSTM gate epilogue (validated shuffle structure), M=32 (2 mtiles), N=16.
__device__ __forceinline__ void lstm_epi(f32x4& acc0, f32x4& acc1,
    const float (&bias4)[4], float* cst, u16* dst, int pw, int wg, int lane)
{
  const int col = lane & 15, kg = lane >> 4, c4 = col & 3;
  #pragma unroll
  for (int mt = 0; mt < 2; ++mt){
    f32x4 accm = mt ? acc1 : acc0;
    #pragma unroll
    for (int r = 0; r < 4; ++r){
      float v  = accm[r];
      float vf = __shfl(v, (lane + 4) & 63);
      float vg = __shfl(v, (lane + 8) & 63);
      float vo = __shfl(v, (lane + 12) & 63);
      float vi = v + bias4[0];           // garbage on col>=4 lanes, unused
      vf += bias4[1]; vg += bias4[2]; vo += bias4[3];
      float co = cst[mt*4 + r];
      float cn = sigm(vf)*co + sigm(vi)*tanhf_(vg);
      if (col < 4) cst[mt*4 + r] = cn;
      float hv = sigm(vo)*tanhf_(cn);
      if (col < 4)
        dst[(pw*32 + mt*16 + kg*4 + r)*512 + wg*4 + c4] = f2bf(hv);
    }
  }
  acc0 = (f32x4){0.f,0.f,0.f,0.f};
  acc1 = (f32x4){0.f,0.f,0.f,0.f};
}

__global__ __launch_bounds__(NTHR, 2) void lstm_ae_kernel(
  const float* __restrict__ initial_hidden,
  const float* __restrict__ Wih0, const float* __restrict__ Whh0,
  const float* __restrict__ bih0, const float* __restrict__ bhh0,
  const float* __restrict__ Wih1, const float* __restrict__ Whh1,
  const float* __restrict__ bih1, const float* __restrict__ bhh1,
  const float* __restrict__ Wlin, const float* __restrict__ blin,
  const int* __restrict__ seqp,
  float* __restrict__ dout, char* __restrict__ ws)
{
  __shared__ float sw[16*256];     // this WG's 16 Wih0 rows (f32)
  __shared__ float we16[16*512];   // Weff = Wih0_slice @ Wlin (f32)
  __shared__ float s_b0[16], s_b1[16];

  const int tid = threadIdx.x, wg = blockIdx.x;
  const int w = tid >> 6, lane = tid & 63;
  const int col = lane & 15, kg = lane >> 4;
  const int pw = w & 3, role = w >> 2;       // role 0 = layer0, 1 = layer1
  const int T = seqp[0];

  unsigned* bar = (unsigned*)ws;             // 128 x 64B arrival lines
  u16* h0b[2];
  h0b[0] = (u16*)(ws + 8192);
  h0b[1] = h0b[0] + 65536;
  u16* wlinb = h0b[1] + 65536;               // Wlin bf16 [256][512]
  u16* hist  = (u16*)dout;                   // h1 history: slot j = 65536 u16

  // ---------------- prologue ----------------
  // 1) stage Wih0 rows
  for (int it = tid; it < 16*256; it += NTHR){
    const int rr = it >> 8, d = it & 255;
    const int j = (rr >> 2)*512 + wg*4 + (rr & 3);
    sw[it] = Wih0[j*256 + d];
  }
  __syncthreads();
  // 2) we16 = sw @ Wlin (each thread one column c = tid)
  {
    const int c = tid;
    float a16[16];
    #pragma unroll
    for (int rr = 0; rr < 16; ++rr) a16[rr] = 0.f;
    for (int d = 0; d < 256; ++d){
      const float wl = Wlin[d*512 + c];
      #pragma unroll
      for (int rr = 0; rr < 16; ++rr) a16[rr] += sw[rr*256 + d] * wl;
    }
    #pragma unroll
    for (int rr = 0; rr < 16; ++rr) we16[rr*512 + c] = a16[rr];
  }
  // 3) biases
  if (tid < 16){
    const int rr = tid;
    const int j = (rr >> 2)*512 + wg*4 + (rr & 3);
    float s = bih0[j] + bhh0[j];
    for (int d = 0; d < 256; ++d) s += sw[rr*256 + d] * blin[d];
    s_b0[rr] = s;
  } else if (tid < 32){
    const int rr = tid - 16;
    const int j = (rr >> 2)*512 + wg*4 + (rr & 3);
    s_b1[rr] = bih1[j] + bhh1[j];
  }
  __syncthreads();
  // 4) weight fragments -> registers (128 VGPRs/wave), pinned
  bf16x8 bw[32];
  {
    const int j_col = (col >> 2)*512 + wg*4 + (col & 3);
    if (role == 0){
      #pragma unroll
      for (int ks = 0; ks < 16; ++ks)
        bw[ks] = load8cvt(&we16[col*512 + ks*32 + kg*8]);
      #pragma unroll
      for (int ks = 0; ks < 16; ++ks)
        bw[16 + ks] = load8cvt(Whh0 + (size_t)j_col*512 + ks*32 + kg*8);
    } else {
      #pragma unroll
      for (int ks = 0; ks < 16; ++ks)
        bw[ks] = load8cvt(Wih1 + (size_t)j_col*512 + ks*32 + kg*8);
      #pragma unroll
      for (int ks = 0; ks < 16; ++ks)
        bw[16 + ks] = load8cvt(Whh1 + (size_t)j_col*512 + ks*32 + kg*8);
    }
    #pragma unroll
    for (int t = 0; t < 32; ++t) asm volatile("" : "+v"(bw[t]));
  }
  // 5) h inits + wlinb (disjoint per-WG slices)
  {
    const int i = wg*512 + tid;
    h0b[0][i] = f2bf(initial_hidden[65536 + i]);                  // h0(0)
    hist[(size_t)(T - 1)*65536 + i] = f2bf(initial_hidden[i]);    // h1(0)
    wlinb[wg*1024 + tid]       = f2bf(Wlin[wg*1024 + tid]);
    wlinb[wg*1024 + 512 + tid] = f2bf(Wlin[wg*1024 + 512 + tid]);
  }
  // per-lane bias registers
  const float* sb = (role == 0) ? s_b0 : s_b1;
  const int c4 = col & 3;
  const float bias4[4] = { sb[c4], sb[4 + c4], sb[8 + c4], sb[12 + c4] };

  unsigned barno = 0;
  gridbar(bar, ++barno, wg);   // publish h0(0), h1(0), wlinb

  f32x4 acc0 = {0.f,0.f,0.f,0.f}, acc1 = {0.f,0.f,0.f,0.f};
  float cst[8] = {0.f,0.f,0.f,0.f,0.f,0.f,0.f,0.f};

  // pre-loop prefetch: layer0 accumulates Whh0·h0(0)
  if (role == 0) gemm_half<16>(bw, h0b[0], acc0, acc1, pw, lane);

  // ---------------- sequential loop: 2 windows per step ----------------
  for (int s = 1; s < T; ++s){
    const u16* h1p = hist + (size_t)(T - s)*65536;   // h1(s-1), fresh
    u16* h0n = h0b[s & 1];
    // window A: layer0 finishes (Weff·h1 + prefetched Whh0·h0) -> h0(s);
    //           layer1 prefetches Whh1·h1(s-1)
    if (role == 0){
      gemm_half<0>(bw, h1p, acc0, acc1, pw, lane);
      lstm_epi(acc0, acc1, bias4, cst, h0n, pw, wg, lane);
    } else {
      gemm_half<16>(bw, h1p, acc0, acc1, pw, lane);
    }
    gridbar(bar, ++barno, wg);
    // window B: layer1 finishes (Wih1·h0(s) + prefetched Whh1·h1) -> h1(s);
    //           layer0 prefetches Whh0·h0(s) for step s+1
    if (role == 1){
      gemm_half<0>(bw, h0n, acc0, acc1, pw, lane);
      lstm_epi(acc0, acc1, bias4, cst,
               hist + (size_t)(T - 1 - s)*65536, pw, wg, lane);
    } else {
      gemm_half<16>(bw, h0n, acc0, acc1, pw, lane);
    }
    gridbar(bar, ++barno, wg);
  }

  // ---------------- output epilogue: out[j] = hist[j] @ Wlin^T + blin ------
  // slot j per (wg, role); 4 waves (pw) cover the 128 rows; in-place safe:
  // each wave fully loads its rows (bf16) before writing the same bytes (f32).
  const int j = wg*2 + role;
  if (j < T){
    const u16* hsl = hist + (size_t)j*65536;
    float* osl = dout + (size_t)j*32768;
    const int mrow = pw*32;
    bf16x8 a[32];
    #pragma unroll
    for (int t = 0; t < 32; ++t){
      const int mt = t >> 4, ks = t & 15;
      a[t] = *(const bf16x8*)(hsl + (mrow + mt*16 + col)*512 + ks*32 + kg*8);
    }
    #pragma unroll
    for (int nb = 0; nb < 16; ++nb){
      f32x4 o0 = {0.f,0.f,0.f,0.f}, o1 = {0.f,0.f,0.f,0.f};
      #pragma unroll
      for (int ks = 0; ks < 16; ++ks){
        bf16x8 b = *(const bf16x8*)(wlinb + (nb*16 + col)*512 + ks*32 + kg*8);
        o0 = __builtin_amdgcn_mfma_f32_16x16x32_bf16(a[ks],      b, o0, 0, 0, 0);
        o1 = __builtin_amdgcn_mfma_f32_16x16x32_bf16(a[16 + ks], b, o1, 0, 0, 0);
      }
      const float bl = blin[nb*16 + col];
      #pragma unroll
      for (int r = 0; r < 4; ++r){
        osl[(mrow      + kg*4 + r)*256 + nb*16 + col] = o0[r] + bl;
        osl[(mrow + 16 + kg*4 + r)*256 + nb*16 + col] = o1[r] + bl;
      }
    }
  }
}

extern "C" void kernel_launch(void* const* d_in, const int* in_sizes, int n_in,
                              void* d_out, int out_size, void* d_ws, size_t ws_size,
                              hipStream_t stream) {
  const float* initial_hidden = (const float*)d_in[0];
  const float* Wih0 = (const float*)d_in[1];
  const float* Whh0 = (const float*)d_in[2];
  const float* bih0 = (const float*)d_in[3];
  const float* bhh0 = (const float*)d_in[4];
  const float* Wih1 = (const float*)d_in[5];
  const float* Whh1 = (const float*)d_in[6];
  const float* bih1 = (const float*)d_in[7];
  const float* bhh1 = (const float*)d_in[8];
  const float* Wlin = (const float*)d_in[9];
  const float* blin = (const float*)d_in[10];
  const int*   seqp = (const int*)d_in[11];

  hipMemsetAsync(d_ws, 0, 8192, stream);
  lstm_ae_kernel<<<dim3(NWG), dim3(NTHR), 0, stream>>>(
      initial_hidden, Wih0, Whh0, bih0, bhh0, Wih1, Whh1, bih1, bhh1,
      Wlin, blin, seqp, (float*)d_out, (char*)d_ws);
}

// Round 8
// 9372.206 us; speedup vs baseline: 1.6614x; 1.1175x over previous
//
#include <hip/hip_runtime.h>
#include <hip/hip_bf16.h>

#define NWG  64
#define NTHR 512

typedef __attribute__((ext_vector_type(8))) short bf16x8;
typedef __attribute__((ext_vector_type(4))) float f32x4;
typedef unsigned short u16;

__device__ __forceinline__ float sigm(float x){ return 1.f/(1.f+__expf(-x)); }
__device__ __forceinline__ float tanhf_(float x){ return 1.f - 2.f/(1.f+__expf(2.f*x)); }
__device__ __forceinline__ u16 f2bf(float x){
  union { float f; unsigned u; } v; v.f = x;
  return (u16)((v.u + 0x7fffu + ((v.u >> 16) & 1u)) >> 16);
}
__device__ __forceinline__ bf16x8 load8cvt(const float* p){
  f32x4 x0 = *(const f32x4*)p;
  f32x4 x1 = *(const f32x4*)(p + 4);
  union { u16 h[8]; bf16x8 v; } u;
  #pragma unroll
  for (int e = 0; e < 4; ++e){ u.h[e] = f2bf(x0[e]); u.h[4+e] = f2bf(x1[e]); }
  return u.v;
}

// Half-fence barrier: h was published via ATOMIC sc1 stores (LLC-direct,
// R4-validated visible after vmcnt drain) -> NO release fence needed.
// Consumers still need the acquire inv (their L1/L2 hold stale h lines).
__device__ __forceinline__ void gridbar(unsigned* bar, unsigned barno, int wg){
  __syncthreads();   // drains vmcnt: all atomic h-stores are in LLC
  if (threadIdx.x == 0)
    __hip_atomic_store(&bar[wg*16], barno, __ATOMIC_RELAXED, __HIP_MEMORY_SCOPE_AGENT);
  if (threadIdx.x < 64){
    const unsigned* f = &bar[threadIdx.x*16];
    while (__hip_atomic_load(f, __ATOMIC_RELAXED, __HIP_MEMORY_SCOPE_AGENT) < barno)
      __builtin_amdgcn_s_sleep(2);
    __builtin_amdgcn_fence(__ATOMIC_ACQUIRE, "agent");
  }
  __syncthreads();
}
// Full-fence barrier: once after prologue (publishes PLAIN-stored ws data).
__device__ __forceinline__ void gridbar_full(unsigned* bar, unsigned barno, int wg){
  __syncthreads();
  if (threadIdx.x == 0){
    __builtin_amdgcn_fence(__ATOMIC_RELEASE, "agent");
    __hip_atomic_store(&bar[wg*16], barno, __ATOMIC_RELAXED, __HIP_MEMORY_SCOPE_AGENT);
  }
  if (threadIdx.x < 64){
    const unsigned* f = &bar[threadIdx.x*16];
    while (__hip_atomic_load(f, __ATOMIC_RELAXED, __HIP_MEMORY_SCOPE_AGENT) < barno)
      __builtin_amdgcn_s_sleep(2);
    __builtin_amdgcn_fence(__ATOMIC_ACQUIRE, "agent");
  }
  __syncthreads();
}

// Dependent GEMM: acc[mt] += h(rows mh*64..+64) @ bw^T, K=512.
// B in registers; A double-buffered bursts of 16 frags.
__device__ __forceinline__ void dep_gemm(const bf16x8 (&bw)[16], const u16* h,
    f32x4 (&acc)[4], int mh, int lane)
{
  const int col = lane & 15, kg = lane >> 4;
  const u16* base = h + (mh*64 + col)*512 + kg*8;
  bf16x8 A0[16], A1[16];
  #pragma unroll
  for (int ks = 0; ks < 16; ++ks) A0[ks] = *(const bf16x8*)(base + ks*32);
  #pragma unroll
  for (int ks = 0; ks < 16; ++ks) A1[ks] = *(const bf16x8*)(base + 16*512 + ks*32);
  #pragma unroll
  for (int ks = 0; ks < 16; ++ks)
    acc[0] = __builtin_amdgcn_mfma_f32_16x16x32_bf16(A0[ks], bw[ks], acc[0], 0, 0, 0);
  #pragma unroll
  for (int ks = 0; ks < 16; ++ks) A0[ks] = *(const bf16x8*)(base + 32*512 + ks*32);
  #pragma unroll
  for (int ks = 0; ks < 16; ++ks)
    acc[1] = __builtin_amdgcn_mfma_f32_16x16x32_bf16(A1[ks], bw[ks], acc[1], 0, 0, 0);
  #pragma unroll
  for (int ks = 0; ks < 16; ++ks) A1[ks] = *(const bf16x8*)(base + 48*512 + ks*32);
  #pragma unroll
  for (int ks = 0; ks < 16; ++ks)
    acc[2] = __builtin_amdgcn_mfma_f32_16x16x32_bf16(A0[ks], bw[ks], acc[2], 0, 0, 0);
  #pragma unroll
  for (int ks = 0; ks < 16; ++ks)
    acc[3] = __builtin_amdgcn_mfma_f32_16x16x32_bf16(A1[ks], bw[ks], acc[3], 0, 0, 0);
}

// Prefetch GEMM (off critical path): B from LDS (swizzled), A bursts of 16.
__device__ __forceinline__ void pre_gemm(const u16* wlds, const u16* h,
    f32x4 (&acc)[4], int mh, int rr_col, int lane)
{
  const int col = lane & 15, kg = lane >> 4;
  const int xr = (rr_col & 7) << 3;
  bf16x8 B[16];
  #pragma unroll
  for (int ks = 0; ks < 16; ++ks)
    B[ks] = *(const bf16x8*)(wlds + rr_col*512 + ((ks*32 + kg*8) ^ xr));
  const u16* base = h + (mh*64 + col)*512 + kg*8;
  #pragma unroll
  for (int mt = 0; mt < 4; ++mt){
    bf16x8 A[16];
    #pragma unroll
    for (int ks = 0; ks < 16; ++ks) A[ks] = *(const bf16x8*)(base + mt*16*512 + ks*32);
    #pragma unroll
    for (int ks = 0; ks < 16; ++ks)
      acc[mt] = __builtin_amdgcn_mfma_f32_16x16x32_bf16(A[ks], B[ks], acc[mt], 0, 0, 0);
  }
}

// LSTM gate epilogue (validated structure); h-stores = relaxed atomic sc1.
__device__ __forceinline__ void lstm_epi(f32x4 (&acc)[4], const float (&bias4)[4],
    float* cst, u16* dst, int mh, int colbase, int lane)
{
  const int col = lane & 15, kg = lane >> 4, c4 = col & 3;
  #pragma unroll
  for (int mt = 0; mt < 4; ++mt){
    #pragma unroll
    for (int r = 0; r < 4; ++r){
      float v  = acc[mt][r];
      float vf = __shfl(v, (lane + 4) & 63);
      float vg = __shfl(v, (lane + 8) & 63);
      float vo = __shfl(v, (lane + 12) & 63);
      float vi = v + bias4[0];
      vf += bias4[1]; vg += bias4[2]; vo += bias4[3];
      float co = cst[mt*4 + r];
      float cn = sigm(vf)*co + sigm(vi)*tanhf_(vg);
      if (col < 4) cst[mt*4 + r] = cn;
      float hv = sigm(vo)*tanhf_(cn);
      unsigned hb = f2bf(hv);
      unsigned hp = __shfl(hb, lane ^ 1);
      if (col < 4 && !(col & 1))
        __hip_atomic_store((unsigned*)(dst + (mh*64 + mt*16 + kg*4 + r)*512 + colbase + c4),
                           hb | (hp << 16), __ATOMIC_RELAXED, __HIP_MEMORY_SCOPE_AGENT);
    }
    acc[mt] = (f32x4){0.f,0.f,0.f,0.f};
  }
}

// Output tile (R3-validated mapping), non-temporal dout stores.
__device__ __forceinline__ void out_tile(const u16* h1p, const u16* wlinb,
    const float* blin, float* dout, int slot, int wg, int w01, int lane)
{
  const int col = lane & 15, kg = lane >> 4;
  const int cb = (wg & 15) * 16;
  const int orow = (wg >> 4) * 32 + w01 * 16;
  f32x4 acc = {0.f,0.f,0.f,0.f};
  const int ao = (orow + col) * 512 + kg*8;
  const int bo = (cb + col) * 512 + kg*8;
  #pragma unroll
  for (int ks = 0; ks < 16; ++ks){
    bf16x8 a = *(const bf16x8*)(h1p + ao + ks*32);
    bf16x8 b = *(const bf16x8*)(wlinb + bo + ks*32);
    acc = __builtin_amdgcn_mfma_f32_16x16x32_bf16(a, b, acc, 0, 0, 0);
  }
  const float bl = blin[cb + col];
  #pragma unroll
  for (int r = 0; r < 4; ++r)
    __builtin_nontemporal_store(acc[r] + bl,
        &dout[(size_t)slot*32768 + (orow + kg*4 + r)*256 + cb + col]);
}

__global__ __launch_bounds__(NTHR, 2) void lstm_ae_kernel(
  const float* __restrict__ initial_hidden,
  const float* __restrict__ Wih0, const float* __restrict__ Whh0,
  const float* __restrict__ bih0, const float* __restrict__ bhh0,
  const float* __restrict__ Wih1, const float* __restrict__ Whh1,
  const float* __restrict__ bih1, const float* __restrict__ bhh1,
  const float* __restrict__ Wlin, const float* __restrict__ blin,
  const int* __restrict__ seqp,
  float* __restrict__ dout, char* __restrict__ ws)
{
  __shared__ __align__(16) char smem[65536];   // sw(32K)+we16(32K) -> whh(64K)
  __shared__ float s_b0[32], s_b1[32];
  float* sw  = (float*)smem;                   // [32][256] f32
  u16*  we16 = (u16*)(smem + 32768);           // [32][512] bf16 (Weff)
  u16*  whh  = (u16*)smem;                     // later: [2][32][512] bf16 swz

  const int tid = threadIdx.x, wg = blockIdx.x;
  const int w = tid >> 6, lane = tid & 63;
  const int col = lane & 15, kg = lane >> 4, c4 = col & 3;
  const int role = w >> 2, sub = w & 3, ns = sub & 1, mh = sub >> 1;
  const int T = seqp[0];

  unsigned* bar = (unsigned*)ws;               // 64 x 64B flag lines
  u16* h0b[2]; u16* h1b[2];
  h0b[0] = (u16*)(ws + 8192);
  h0b[1] = h0b[0] + 65536;
  h1b[0] = h0b[1] + 65536;
  h1b[1] = h1b[0] + 65536;
  u16* wlinb = h1b[1] + 65536;                 // Wlin bf16 [256][512]

  // ---------------- prologue ----------------
  // 1) stage this WG's 32 Wih0 rows (f32): row rr -> gate row j
  for (int it = tid; it < 32*256; it += NTHR){
    const int rr = it >> 8, d = it & 255;
    const int j = (rr >> 3)*512 + wg*8 + (rr & 7);
    sw[it] = Wih0[j*256 + d];
  }
  __syncthreads();
  // 2) Weff = Wih0_slice @ Wlin -> we16 (bf16); thread = column c
  {
    const int c = tid;
    float a32[32];
    #pragma unroll
    for (int rr = 0; rr < 32; ++rr) a32[rr] = 0.f;
    for (int d = 0; d < 256; ++d){
      const float wl = Wlin[d*512 + c];
      #pragma unroll
      for (int rr = 0; rr < 32; ++rr) a32[rr] += sw[rr*256 + d] * wl;
    }
    #pragma unroll
    for (int rr = 0; rr < 32; ++rr) we16[rr*512 + c] = f2bf(a32[rr]);
  }
  // 3) biases: b0eff = bih0+bhh0+Wih0@blin ; b1 = bih1+bhh1
  if (tid < 32){
    const int rr = tid;
    const int j = (rr >> 3)*512 + wg*8 + (rr & 7);
    float s = bih0[j] + bhh0[j];
    for (int d = 0; d < 256; ++d) s += sw[rr*256 + d] * blin[d];
    s_b0[rr] = s;
  } else if (tid < 64){
    const int rr = tid - 32;
    const int j = (rr >> 3)*512 + wg*8 + (rr & 7);
    s_b1[rr] = bih1[j] + bhh1[j];
  }
  __syncthreads();
  // 4) dependent-half weights -> registers (64 VGPR/wave), pinned
  const int rr_col = (col >> 2)*8 + ns*4 + c4;
  bf16x8 bw[16];
  if (role == 0){
    #pragma unroll
    for (int ks = 0; ks < 16; ++ks)
      bw[ks] = *(const bf16x8*)(we16 + rr_col*512 + ks*32 + kg*8);
  } else {
    const size_t j_col = (size_t)((col >> 2)*512 + wg*8 + ns*4 + c4);
    #pragma unroll
    for (int ks = 0; ks < 16; ++ks)
      bw[ks] = load8cvt(Wih1 + j_col*512 + ks*32 + kg*8);
  }
  #pragma unroll
  for (int t = 0; t < 16; ++t) asm volatile("" : "+v"(bw[t]));
  __syncthreads();   // we16/sw dead -> whh may overwrite
  // 5) prefetch-half weights (Whh0, Whh1) -> LDS bf16, XOR-swizzled
  for (int it = tid; it < 2*32*512; it += NTHR){
    const int layer = it >> 14, rr = (it >> 9) & 31, kk = it & 511;
    const int j = (rr >> 3)*512 + wg*8 + (rr & 7);
    const float* src = layer ? Whh1 : Whh0;
    whh[layer*16384 + rr*512 + (kk ^ ((rr & 7) << 3))] = f2bf(src[(size_t)j*512 + kk]);
  }
  // 6) publish initial state + wlinb (plain stores; gridbar_full fences them)
  for (int i = wg*1024 + tid; i < (wg + 1)*1024; i += NTHR){
    h0b[0][i] = f2bf(initial_hidden[65536 + i]);
    h1b[0][i] = f2bf(initial_hidden[i]);
  }
  for (int i = wg*2048 + tid; i < (wg + 1)*2048; i += NTHR){
    wlinb[i] = f2bf(Wlin[i]);
  }
  __syncthreads();   // whh ready for this WG's waves
  // per-lane bias registers
  const float* sb = role ? s_b1 : s_b0;
  const float bias4[4] = { sb[ns*4 + c4], sb[8 + ns*4 + c4],
                           sb[16 + ns*4 + c4], sb[24 + ns*4 + c4] };
  const u16* whh_my = whh + role*16384;
  const int colbase = wg*8 + ns*4;

  unsigned barno = 0;
  gridbar_full(bar, ++barno, wg);

  f32x4 acc[4] = {{0.f,0.f,0.f,0.f},{0.f,0.f,0.f,0.f},{0.f,0.f,0.f,0.f},{0.f,0.f,0.f,0.f}};
  float cst[16];
  #pragma unroll
  for (int q = 0; q < 16; ++q) cst[q] = 0.f;

  // pre-loop: layer0 prefetches Whh0·h0(0)
  if (role == 0) pre_gemm(whh_my, h0b[0], acc, mh, rr_col, lane);

  // ---------------- sequential loop ----------------
  int p = 0;
  for (int s = 1; s < T; ++s){
    const u16* h1p = h1b[p];
    u16* h0n = h0b[p ^ 1];
    u16* h1n = h1b[p ^ 1];
    // window A: role0 finishes gates0 (Weff·h1 + prefetched Whh0·h0) -> h0(s)
    //           role1 prefetches Whh1·h1(s-1)
    if (role == 0){
      dep_gemm(bw, h1p, acc, mh, lane);
      lstm_epi(acc, bias4, cst, h0n, mh, colbase, lane);
    } else {
      pre_gemm(whh_my, h1p, acc, mh, rr_col, lane);
    }
    gridbar(bar, ++barno, wg);
    // window B: role1 finishes gates1 (Wih1·h0(s) + prefetched Whh1·h1) -> h1(s)
    //           role0 prefetches Whh0·h0(s); waves 0,1 also emit out(s-1)
    if (role == 1){
      dep_gemm(bw, h0n, acc, mh, lane);
      lstm_epi(acc, bias4, cst, h1n, mh, colbase, lane);
    } else {
      pre_gemm(whh_my, h0n, acc, mh, rr_col, lane);
      if (w < 2) out_tile(h1p, wlinb, blin, dout, T - s, wg, w, lane);
    }
    gridbar(bar, ++barno, wg);
    p ^= 1;
  }
  if (w < 2) out_tile(h1b[p], wlinb, blin, dout, 0, wg, w, lane);
}

extern "C" void kernel_launch(void* const* d_in, const int* in_sizes, int n_in,
                              void* d_out, int out_size, void* d_ws, size_t ws_size,
                              hipStream_t stream) {
  const float* initial_hidden = (const float*)d_in[0];
  const float* Wih0 = (const float*)d_in[1];
  const float* Whh0 = (const float*)d_in[2];
  const float* bih0 = (const float*)d_in[3];
  const float* bhh0 = (const float*)d_in[4];
  const float* Wih1 = (const float*)d_in[5];
  const float* Whh1 = (const float*)d_in[6];
  const float* bih1 = (const float*)d_in[7];
  const float* bhh1 = (const float*)d_in[8];
  const float* Wlin = (const float*)d_in[9];
  const float* blin = (const float*)d_in[10];
  const int*   seqp = (const int*)d_in[11];

  hipMemsetAsync(d_ws, 0, 8192, stream);
  lstm_ae_kernel<<<dim3(NWG), dim3(NTHR), 0, stream>>>(
      initial_hidden, Wih0, Whh0, bih0, bhh0, Wih1, Whh1, bih1, bhh1,
      Wlin, blin, seqp, (float*)d_out, (char*)d_ws);
}

// Round 9
// 7599.132 us; speedup vs baseline: 2.0491x; 1.2333x over previous
//
#include <hip/hip_runtime.h>
#include <hip/hip_bf16.h>

typedef __attribute__((ext_vector_type(8))) short bf16x8;
typedef __attribute__((ext_vector_type(4))) float f32x4;
typedef unsigned short u16;

#define T_SEQ 256

__device__ __forceinline__ float sigm(float x){ return 1.f/(1.f+__expf(-x)); }
__device__ __forceinline__ float tanhf_(float x){ return 1.f - 2.f/(1.f+__expf(2.f*x)); }
__device__ __forceinline__ u16 f2bf(float x){
  union { float f; unsigned u; } v; v.f = x;
  return (u16)((v.u + 0x7fffu + ((v.u >> 16) & 1u)) >> 16);
}
__device__ __forceinline__ bf16x8 load8cvt(const float* p){
  f32x4 x0 = *(const f32x4*)p;
  f32x4 x1 = *(const f32x4*)(p + 4);
  union { u16 h[8]; bf16x8 v; } u;
  #pragma unroll
  for (int e = 0; e < 4; ++e){ u.h[e] = f2bf(x0[e]); u.h[4+e] = f2bf(x1[e]); }
  return u.v;
}

// ---------------- setup: one-time weight prep + state init ----------------
// grid 256 x 256. Each WG owns 8 gate rows for Weff/b0eff/b1, plus strided
// slices of the bf16 conversions and state inits.
__global__ __launch_bounds__(256) void setup_kernel(
  const float* __restrict__ initial_hidden,
  const float* __restrict__ Wih0, const float* __restrict__ Whh0,
  const float* __restrict__ bih0, const float* __restrict__ bhh0,
  const float* __restrict__ Wih1, const float* __restrict__ Whh1,
  const float* __restrict__ bih1, const float* __restrict__ bhh1,
  const float* __restrict__ Wlin, const float* __restrict__ blin,
  u16* __restrict__ Weff, u16* __restrict__ Whh0b,
  u16* __restrict__ Wih1b, u16* __restrict__ Whh1b,
  float* __restrict__ b0eff, float* __restrict__ b1,
  u16* __restrict__ h0b0, u16* __restrict__ hist_last,
  float* __restrict__ c0, float* __restrict__ c1)
{
  __shared__ float sw[8*256];
  const int tid = threadIdx.x, bid = blockIdx.x;

  // bf16 conversions of the three recurrent/input weight matrices
  for (int i = bid*256 + tid; i < 2048*512; i += 256*256){
    Whh0b[i] = f2bf(Whh0[i]);
    Wih1b[i] = f2bf(Wih1[i]);
    Whh1b[i] = f2bf(Whh1[i]);
  }
  // state inits (65536 elements each, exactly one per thread)
  {
    const int i = bid*256 + tid;
    h0b0[i]      = f2bf(initial_hidden[65536 + i]);   // h0(0) = hidden[1]
    hist_last[i] = f2bf(initial_hidden[i]);           // h1(0) -> slot T-1
    c0[i] = 0.f; c1[i] = 0.f;
  }
  // stage this WG's 8 Wih0 rows (contiguous) into LDS
  for (int it = tid; it < 8*256; it += 256) sw[it] = Wih0[bid*8*256 + it];
  __syncthreads();
  // Weff rows bid*8..+8 : Weff = Wih0 @ Wlin (f32 accum, bf16 store)
  for (int cc = tid; cc < 512; cc += 256){
    float a8[8];
    #pragma unroll
    for (int rr = 0; rr < 8; ++rr) a8[rr] = 0.f;
    for (int d = 0; d < 256; ++d){
      const float wl = Wlin[d*512 + cc];
      #pragma unroll
      for (int rr = 0; rr < 8; ++rr) a8[rr] += sw[rr*256 + d] * wl;
    }
    #pragma unroll
    for (int rr = 0; rr < 8; ++rr) Weff[(bid*8 + rr)*512 + cc] = f2bf(a8[rr]);
  }
  // biases: b0eff = bih0 + bhh0 + Wih0 @ blin ; b1 = bih1 + bhh1
  if (tid < 8){
    const int r = bid*8 + tid;
    float s = bih0[r] + bhh0[r];
    for (int d = 0; d < 256; ++d) s += sw[tid*256 + d] * blin[d];
    b0eff[r] = s;
    b1[r] = bih1[r] + bhh1[r];
  }
}

// ---------------- one LSTM layer step (one graph node) ----------------
// gates = A1 @ W1^T + A2 @ W2^T + bias -> h_dst (bf16), c state updated.
// A1,A2: [128][512] bf16. W1,W2: [2048][512] bf16. grid 128 x 256.
// WG wg owns hidden units wg*4..+4 (gate rows {gi*512 + wg*4 + u}).
__global__ __launch_bounds__(256) void step_kernel(
  const u16* __restrict__ A1, const u16* __restrict__ W1,
  const u16* __restrict__ A2, const u16* __restrict__ W2,
  const float* __restrict__ bias, u16* __restrict__ hdst,
  float* __restrict__ cst)
{
  const int wg = blockIdx.x;
  const int w = threadIdx.x >> 6, lane = threadIdx.x & 63;
  const int col = lane & 15, kg = lane >> 4;
  const int gi = col >> 2, u = col & 3;
  const size_t grow = (size_t)(gi*512 + wg*4 + u);

  // B fragments -> registers (one 16-gate-row slice per matrix)
  bf16x8 bw1[16], bw2[16];
  {
    const u16* w1p = W1 + grow*512 + kg*8;
    const u16* w2p = W2 + grow*512 + kg*8;
    #pragma unroll
    for (int ks = 0; ks < 16; ++ks) bw1[ks] = *(const bf16x8*)(w1p + ks*32);
    #pragma unroll
    for (int ks = 0; ks < 16; ++ks) bw2[ks] = *(const bf16x8*)(w2p + ks*32);
  }
  // per-lane biases (i/f/g/o for hidden unit wg*4+u)
  const int hid = wg*4 + u;
  const float b_i = bias[hid], b_f = bias[512 + hid],
              b_g = bias[1024 + hid], b_o = bias[1536 + hid];
  // c preload (meaningful on col<4 lanes)
  float cv[8];
  #pragma unroll
  for (int mt = 0; mt < 2; ++mt)
    #pragma unroll
    for (int r = 0; r < 4; ++r)
      cv[mt*4 + r] = cst[(w*32 + mt*16 + kg*4 + r)*512 + hid];

  // GEMM: rows w*32..+32 (2 m-tiles), K = 512 + 512
  f32x4 acc0 = {0.f,0.f,0.f,0.f}, acc1 = {0.f,0.f,0.f,0.f};
  const u16* a1p = A1 + (w*32 + col)*512 + kg*8;
  const u16* a2p = A2 + (w*32 + col)*512 + kg*8;
  #pragma unroll
  for (int ks = 0; ks < 16; ++ks){
    bf16x8 x0 = *(const bf16x8*)(a1p + ks*32);
    bf16x8 x1 = *(const bf16x8*)(a1p + 16*512 + ks*32);
    acc0 = __builtin_amdgcn_mfma_f32_16x16x32_bf16(x0, bw1[ks], acc0, 0, 0, 0);
    acc1 = __builtin_amdgcn_mfma_f32_16x16x32_bf16(x1, bw1[ks], acc1, 0, 0, 0);
  }
  #pragma unroll
  for (int ks = 0; ks < 16; ++ks){
    bf16x8 x0 = *(const bf16x8*)(a2p + ks*32);
    bf16x8 x1 = *(const bf16x8*)(a2p + 16*512 + ks*32);
    acc0 = __builtin_amdgcn_mfma_f32_16x16x32_bf16(x0, bw2[ks], acc0, 0, 0, 0);
    acc1 = __builtin_amdgcn_mfma_f32_16x16x32_bf16(x1, bw2[ks], acc1, 0, 0, 0);
  }

  // LSTM cell epilogue (validated shuffle structure)
  #pragma unroll
  for (int mt = 0; mt < 2; ++mt){
    f32x4 am = mt ? acc1 : acc0;
    #pragma unroll
    for (int r = 0; r < 4; ++r){
      float v  = am[r];
      float vf = __shfl(v, (lane + 4) & 63);
      float vg = __shfl(v, (lane + 8) & 63);
      float vo = __shfl(v, (lane + 12) & 63);
      float vi = v + b_i;
      vf += b_f; vg += b_g; vo += b_o;
      float co = cv[mt*4 + r];
      float cn = sigm(vf)*co + sigm(vi)*tanhf_(vg);
      float hv = sigm(vo)*tanhf_(cn);
      const int row = w*32 + mt*16 + kg*4 + r;
      if (col < 4) cst[row*512 + hid] = cn;
      unsigned hb = f2bf(hv);
      unsigned hp = __shfl(hb, lane ^ 1);
      if (col < 4 && !(col & 1))
        *(unsigned*)(hdst + row*512 + wg*4 + col) = hb | (hp << 16);
    }
  }
}

// ---------------- batched output GEMM: out[j] = hist[j] @ Wlin^T + blin ----
// grid 256 x 256; WG = one slot; in-place over the bf16 history (each wave
// reads only its own 32 rows and waits vmcnt(0) before overwriting them).
__global__ __launch_bounds__(256) void out_kernel(
  float* __restrict__ dout, const float* __restrict__ Wlin,
  const float* __restrict__ blin)
{
  const int slot = blockIdx.x;
  const u16* hsl = (const u16*)dout + (size_t)slot*65536;
  float* osl = dout + (size_t)slot*32768;
  const int w = threadIdx.x >> 6, lane = threadIdx.x & 63;
  const int col = lane & 15, kg = lane >> 4;

  bf16x8 a[32];
  const u16* ap = hsl + (w*32 + col)*512 + kg*8;
  #pragma unroll
  for (int t = 0; t < 32; ++t){
    const int mt = t >> 4, ks = t & 15;
    a[t] = *(const bf16x8*)(ap + mt*16*512 + ks*32);
  }
  asm volatile("s_waitcnt vmcnt(0)" ::: "memory");   // reads before in-place writes

  #pragma unroll
  for (int nb = 0; nb < 16; ++nb){
    f32x4 o0 = {0.f,0.f,0.f,0.f}, o1 = {0.f,0.f,0.f,0.f};
    #pragma unroll
    for (int ks = 0; ks < 16; ++ks){
      bf16x8 b = load8cvt(Wlin + (nb*16 + col)*512 + ks*32 + kg*8);
      o0 = __builtin_amdgcn_mfma_f32_16x16x32_bf16(a[ks],      b, o0, 0, 0, 0);
      o1 = __builtin_amdgcn_mfma_f32_16x16x32_bf16(a[16 + ks], b, o1, 0, 0, 0);
    }
    const float bl = blin[nb*16 + col];
    #pragma unroll
    for (int r = 0; r < 4; ++r){
      osl[(w*32      + kg*4 + r)*256 + nb*16 + col] = o0[r] + bl;
      osl[(w*32 + 16 + kg*4 + r)*256 + nb*16 + col] = o1[r] + bl;
    }
  }
}

extern "C" void kernel_launch(void* const* d_in, const int* in_sizes, int n_in,
                              void* d_out, int out_size, void* d_ws, size_t ws_size,
                              hipStream_t stream) {
  const float* initial_hidden = (const float*)d_in[0];
  const float* Wih0 = (const float*)d_in[1];
  const float* Whh0 = (const float*)d_in[2];
  const float* bih0 = (const float*)d_in[3];
  const float* bhh0 = (const float*)d_in[4];
  const float* Wih1 = (const float*)d_in[5];
  const float* Whh1 = (const float*)d_in[6];
  const float* bih1 = (const float*)d_in[7];
  const float* bhh1 = (const float*)d_in[8];
  const float* Wlin = (const float*)d_in[9];
  const float* blin = (const float*)d_in[10];

  char* W = (char*)d_ws;
  u16* Weff  = (u16*)W;                          // [2048][512] bf16, 2MB
  u16* Whh0b = (u16*)(W + (2u << 20));           // 2MB
  u16* Wih1b = (u16*)(W + (4u << 20));           // 2MB
  u16* Whh1b = (u16*)(W + (6u << 20));           // 2MB
  float* b0eff = (float*)(W + (8u << 20));                 // 8KB
  float* b1    = (float*)(W + (8u << 20) + 8192);          // 8KB
  u16* h0b[2];
  h0b[0] = (u16*)(W + (8u << 20) + 16384);                 // 128KB
  h0b[1] = (u16*)(W + (8u << 20) + 16384 + 131072);        // 128KB
  float* c0 = (float*)(W + (8u << 20) + 16384 + 262144);   // 256KB
  float* c1 = (float*)(W + (8u << 20) + 16384 + 262144 + 262144);

  u16* hist = (u16*)d_out;   // slot k (k = T-1-s holds h1(s)): 65536 u16 each

  setup_kernel<<<dim3(256), dim3(256), 0, stream>>>(
      initial_hidden, Wih0, Whh0, bih0, bhh0, Wih1, Whh1, bih1, bhh1,
      Wlin, blin, Weff, Whh0b, Wih1b, Whh1b, b0eff, b1,
      h0b[0], hist + (size_t)(T_SEQ - 1)*65536, c0, c1);

  for (int s = 1; s < T_SEQ; ++s){
    const u16* h1prev = hist + (size_t)(T_SEQ - s)*65536;      // h1(s-1)
    u16* h1next = hist + (size_t)(T_SEQ - 1 - s)*65536;        // h1(s)
    // layer 0: gates0 = h1(s-1)@Weff^T + h0(s-1)@Whh0^T + b0eff -> h0(s)
    step_kernel<<<dim3(128), dim3(256), 0, stream>>>(
        h1prev, Weff, h0b[(s - 1) & 1], Whh0b, b0eff, h0b[s & 1], c0);
    // layer 1: gates1 = h0(s)@Wih1^T + h1(s-1)@Whh1^T + b1 -> h1(s)
    step_kernel<<<dim3(128), dim3(256), 0, stream>>>(
        h0b[s & 1], Wih1b, h1prev, Whh1b, b1, h1next, c1);
  }

  out_kernel<<<dim3(256), dim3(256), 0, stream>>>((float*)d_out, Wlin, blin);
}

// Round 11
// 6023.359 us; speedup vs baseline: 2.5852x; 1.2616x over previous
//
#include <hip/hip_runtime.h>
#include <hip/hip_bf16.h>

#define NWG   64
#define NTHR  512
#define HQ    512
#define ROWB  2048
#define W1OFF 65536
#define WLOFF 131072

typedef __attribute__((ext_vector_type(8))) short bf16x8;
typedef __attribute__((ext_vector_type(4))) float f32x4;
typedef unsigned short u16;

__device__ __forceinline__ float sigm(float x){ return 1.f/(1.f+__expf(-x)); }
__device__ __forceinline__ float tanhf_(float x){ return 1.f - 2.f/(1.f+__expf(2.f*x)); }
__device__ __forceinline__ u16 f2bf(float x){
  union { float f; unsigned u; } v; v.f = x;
  return (u16)((v.u + 0x7fffu + ((v.u >> 16) & 1u)) >> 16);
}

// ---- LLC-direct data plane -------------------------------------------------
// Loads: PLAIN (non-atomic) global_load_dwordx4 with sc0 sc1 -> bypass L1/L2,
// read the LLC (coherence point) at full vector-load rate. 16-load batch from
// one base address via imm offsets. Outputs are EARLY-CLOBBER ("=&v") so the
// allocator cannot overlap them with the address pair (R10 crash cause).
// Counted vmcnt waits + sched_barrier(0) stop hipcc hoisting MFMAs past the
// wait (guide rule #18).
__device__ __forceinline__ void llc_load16x(bf16x8 (&A)[16], const u16* p){
  asm volatile(
    "global_load_dwordx4 %0, %16, off sc0 sc1\n\t"
    "global_load_dwordx4 %1, %16, off offset:64 sc0 sc1\n\t"
    "global_load_dwordx4 %2, %16, off offset:128 sc0 sc1\n\t"
    "global_load_dwordx4 %3, %16, off offset:192 sc0 sc1\n\t"
    "global_load_dwordx4 %4, %16, off offset:256 sc0 sc1\n\t"
    "global_load_dwordx4 %5, %16, off offset:320 sc0 sc1\n\t"
    "global_load_dwordx4 %6, %16, off offset:384 sc0 sc1\n\t"
    "global_load_dwordx4 %7, %16, off offset:448 sc0 sc1\n\t"
    "global_load_dwordx4 %8, %16, off offset:512 sc0 sc1\n\t"
    "global_load_dwordx4 %9, %16, off offset:576 sc0 sc1\n\t"
    "global_load_dwordx4 %10, %16, off offset:640 sc0 sc1\n\t"
    "global_load_dwordx4 %11, %16, off offset:704 sc0 sc1\n\t"
    "global_load_dwordx4 %12, %16, off offset:768 sc0 sc1\n\t"
    "global_load_dwordx4 %13, %16, off offset:832 sc0 sc1\n\t"
    "global_load_dwordx4 %14, %16, off offset:896 sc0 sc1\n\t"
    "global_load_dwordx4 %15, %16, off offset:960 sc0 sc1"
    : "=&v"(A[0]),"=&v"(A[1]),"=&v"(A[2]),"=&v"(A[3]),
      "=&v"(A[4]),"=&v"(A[5]),"=&v"(A[6]),"=&v"(A[7]),
      "=&v"(A[8]),"=&v"(A[9]),"=&v"(A[10]),"=&v"(A[11]),
      "=&v"(A[12]),"=&v"(A[13]),"=&v"(A[14]),"=&v"(A[15])
    : "v"(p)
    : "memory");
}
__device__ __forceinline__ void llc_wait16(){
  asm volatile("s_waitcnt vmcnt(16)" ::: "memory");
  __builtin_amdgcn_sched_barrier(0);
}
__device__ __forceinline__ void llc_wait0(){
  asm volatile("s_waitcnt vmcnt(0)" ::: "memory");
  __builtin_amdgcn_sched_barrier(0);
}

// Fence-free grid barrier (R4-validated protocol): all cross-WG data moves
// LLC-direct (atomic sc1 stores / sc1 loads), so no wbl2 and no inv are ever
// needed. __syncthreads drains vmcnt (h-stores are in the LLC before the
// flag goes up; flag store issues after, completes in order at the LLC).
__device__ __forceinline__ void gridbar(unsigned* bar, unsigned barno, int wg){
  __syncthreads();
  if (threadIdx.x == 0)
    __hip_atomic_store(&bar[wg*16], barno, __ATOMIC_RELAXED, __HIP_MEMORY_SCOPE_AGENT);
  if (threadIdx.x < 64){
    const unsigned* f = &bar[threadIdx.x*16];
    while (__hip_atomic_load(f, __ATOMIC_RELAXED, __HIP_MEMORY_SCOPE_AGENT) < barno)
      __builtin_amdgcn_s_sleep(2);
  }
  __syncthreads();
}

// One LSTM layer phase (R3-validated math): gates = [lo|hi] @ Wcat^T + bias.
// A via LLC-direct batched loads; B from LDS (swizzled); h out = atomic sc1.
__device__ __forceinline__ void lstm_phase(
    const char* __restrict__ smemb, int wbase,
    const u16* __restrict__ lo, const u16* __restrict__ hi,
    const float* __restrict__ sbias, u16* __restrict__ dst,
    float* creg, int wg, int w, int lane)
{
  const int col = lane & 15, kg = lane >> 4;
  const int mrow = w * 16;
  f32x4 acc0 = {0.f,0.f,0.f,0.f}, acc1 = {0.f,0.f,0.f,0.f};
  const char* w0 = smemb + wbase + col * ROWB;
  const char* w1 = smemb + wbase + (16 + col) * ROWB;
  const int x0 = (col & 7) << 4;
  bf16x8 A0[16], A1[16];
  llc_load16x(A0, lo + (mrow + col)*HQ + kg*8);
  llc_load16x(A1, hi + (mrow + col)*HQ + kg*8);
  llc_wait16();                      // A0 ready, A1 still in flight
  #pragma unroll
  for (int ks = 0; ks < 16; ++ks){
    const int byt = ks*64 + kg*16;
    bf16x8 b0 = *(const bf16x8*)(w0 + (byt ^ x0));
    bf16x8 b1 = *(const bf16x8*)(w1 + (byt ^ x0));
    acc0 = __builtin_amdgcn_mfma_f32_16x16x32_bf16(A0[ks], b0, acc0, 0, 0, 0);
    acc1 = __builtin_amdgcn_mfma_f32_16x16x32_bf16(A0[ks], b1, acc1, 0, 0, 0);
  }
  llc_wait0();
  #pragma unroll
  for (int ks = 0; ks < 16; ++ks){
    const int byt = 1024 + ks*64 + kg*16;
    bf16x8 b0 = *(const bf16x8*)(w0 + (byt ^ x0));
    bf16x8 b1 = *(const bf16x8*)(w1 + (byt ^ x0));
    acc0 = __builtin_amdgcn_mfma_f32_16x16x32_bf16(A1[ks], b0, acc0, 0, 0, 0);
    acc1 = __builtin_amdgcn_mfma_f32_16x16x32_bf16(A1[ks], b1, acc1, 0, 0, 0);
  }
  const int hcb = wg * 8, c4 = col & 3;
  #pragma unroll
  for (int nt = 0; nt < 2; ++nt){
    f32x4 accm = nt ? acc1 : acc0;
    #pragma unroll
    for (int r = 0; r < 4; ++r){
      float v = accm[r];
      float vf = __shfl(v, (lane + 4) & 63);
      float vg = __shfl(v, (lane + 8) & 63);
      float vo = __shfl(v, (lane + 12) & 63);
      float vi = v + sbias[nt*16 + c4];
      vf += sbias[nt*16 + 4 + c4];
      vg += sbias[nt*16 + 8 + c4];
      vo += sbias[nt*16 + 12 + c4];
      float co = creg[nt*4 + r];
      float cn = sigm(vf)*co + sigm(vi)*tanhf_(vg);
      if (col < 4) creg[nt*4 + r] = cn;
      float hv = sigm(vo)*tanhf_(cn);
      unsigned hb = f2bf(hv);
      unsigned hp = __shfl(hb, lane ^ 1);
      if (col < 4 && !(col & 1)){
        const int row = mrow + kg*4 + r;
        __hip_atomic_store((unsigned*)(dst + row*HQ + hcb + nt*4 + col),
                           hb | (hp << 16), __ATOMIC_RELAXED, __HIP_MEMORY_SCOPE_AGENT);
      }
    }
  }
}

// Output tile: h1 via LLC-direct loads, Wlin slice from LDS, plain dout stores
// (dout is never read cross-WG; end-of-kernel flush publishes it).
__device__ __forceinline__ void out_tile(
    const u16* __restrict__ h1p, const char* __restrict__ wlin_s,
    const float* __restrict__ blin, float* __restrict__ dout,
    int slot, int wg, int w01, int lane)
{
  const int col = lane & 15, kg = lane >> 4;
  const int cb = (wg & 15) * 16;
  const int orow = (wg >> 4) * 32 + w01 * 16;
  bf16x8 a[16];
  llc_load16x(a, h1p + (orow + col)*HQ + kg*8);
  const char* wr = wlin_s + col * 1024;
  const int x0 = (col & 7) << 4;
  llc_wait0();
  f32x4 acc = {0.f,0.f,0.f,0.f};
  #pragma unroll
  for (int ks = 0; ks < 16; ++ks){
    bf16x8 b = *(const bf16x8*)(wr + ((ks*64 + kg*16) ^ x0));
    acc = __builtin_amdgcn_mfma_f32_16x16x32_bf16(a[ks], b, acc, 0, 0, 0);
  }
  const float bl = blin[cb + col];
  #pragma unroll
  for (int r = 0; r < 4; ++r){
    const int row = orow + kg*4 + r;
    dout[(size_t)slot*32768 + row*256 + cb + col] = acc[r] + bl;
  }
}

__global__ __launch_bounds__(NTHR, 2) void lstm_ae_kernel(
  const float* __restrict__ initial_hidden,
  const float* __restrict__ Wih0, const float* __restrict__ Whh0,
  const float* __restrict__ bih0, const float* __restrict__ bhh0,
  const float* __restrict__ Wih1, const float* __restrict__ Whh1,
  const float* __restrict__ bih1, const float* __restrict__ bhh1,
  const float* __restrict__ Wlin, const float* __restrict__ blin,
  const int* __restrict__ seqp,
  float* __restrict__ dout, char* __restrict__ ws)
{
  __shared__ __align__(128) char wsmem[147456];  // W0(64K)+W1(64K)+WlinS(16K)
  __shared__ float s_b0[32], s_b1[32];
  const int tid = threadIdx.x, wg = blockIdx.x;
  const int w = tid >> 6, lane = tid & 63;
  const int T = seqp[0];

  unsigned* bar = (unsigned*)ws;
  u16* h0b[2]; u16* h1b[2];
  h0b[0] = (u16*)(ws + 8192);
  h0b[1] = h0b[0] + 65536;
  h1b[0] = h0b[1] + 65536;
  h1b[1] = h1b[0] + 65536;

  // ---------------- prologue (R3-validated math) ----------------
  float* sw = (float*)(wsmem + W1OFF);
  for (int it = tid; it < 32*256; it += NTHR){
    const int rr = it >> 8, d = it & 255;
    const int j = ((rr >> 2) & 3)*512 + wg*8 + (rr >> 4)*4 + (rr & 3);
    sw[it] = Wih0[j*256 + d];
  }
  __syncthreads();
  {
    float acc[32];
    #pragma unroll
    for (int rr = 0; rr < 32; ++rr) acc[rr] = 0.f;
    for (int d = 0; d < 256; d += 4){
      const float wl0 = Wlin[(d+0)*512 + tid];
      const float wl1 = Wlin[(d+1)*512 + tid];
      const float wl2 = Wlin[(d+2)*512 + tid];
      const float wl3 = Wlin[(d+3)*512 + tid];
      #pragma unroll
      for (int rr = 0; rr < 32; ++rr){
        const f32x4 s4 = *(const f32x4*)(sw + rr*256 + d);
        acc[rr] += s4[0]*wl0 + s4[1]*wl1 + s4[2]*wl2 + s4[3]*wl3;
      }
    }
    #pragma unroll
    for (int rr = 0; rr < 32; ++rr){
      *(u16*)(wsmem + rr*ROWB + ((2*tid) ^ ((rr & 7) << 4))) = f2bf(acc[rr]);
    }
  }
  if (tid < 32){
    const int rr = tid;
    const int j = ((rr >> 2) & 3)*512 + wg*8 + (rr >> 4)*4 + (rr & 3);
    float s = bih0[j] + bhh0[j];
    for (int d = 0; d < 256; ++d) s += sw[rr*256 + d] * blin[d];
    s_b0[rr] = s;
  } else if (tid < 64){
    const int rr = tid - 32;
    const int j = ((rr >> 2) & 3)*512 + wg*8 + (rr >> 4)*4 + (rr & 3);
    s_b1[rr] = bih1[j] + bhh1[j];
  }
  __syncthreads();
  for (int it = tid; it < 32*512; it += NTHR){
    const int rr = it >> 9, kk = it & 511;
    const int j = ((rr >> 2) & 3)*512 + wg*8 + (rr >> 4)*4 + (rr & 3);
    *(u16*)(wsmem + rr*ROWB + ((1024 + 2*kk) ^ ((rr & 7) << 4))) = f2bf(Whh0[j*512 + kk]);
  }
  for (int it = tid; it < 32*1024; it += NTHR){
    const int rr = it >> 10, e = it & 1023;
    const int j = ((rr >> 2) & 3)*512 + wg*8 + (rr >> 4)*4 + (rr & 3);
    const float v = (e < 512) ? Wih1[j*512 + e] : Whh1[j*512 + (e - 512)];
    *(u16*)(wsmem + W1OFF + rr*ROWB + ((2*e) ^ ((rr & 7) << 4))) = f2bf(v);
  }
  // Wlin slice for out_tile -> LDS (rows cb..cb+16), swizzled like weights
  for (int it = tid; it < 16*512; it += NTHR){
    const int rr = it >> 9, kk = it & 511;
    *(u16*)(wsmem + WLOFF + rr*1024 + ((2*kk) ^ ((rr & 7) << 4)))
        = f2bf(Wlin[((wg & 15)*16 + rr)*512 + kk]);
  }
  // initial h -> LLC via atomic sc1 u32 stores (each WG its own 512-u32 slice)
  {
    const int i2 = wg*512 + tid;
    unsigned v0 = (unsigned)f2bf(initial_hidden[65536 + 2*i2])
                | ((unsigned)f2bf(initial_hidden[65536 + 2*i2 + 1]) << 16);
    unsigned v1 = (unsigned)f2bf(initial_hidden[2*i2])
                | ((unsigned)f2bf(initial_hidden[2*i2 + 1]) << 16);
    __hip_atomic_store((unsigned*)h0b[0] + i2, v0, __ATOMIC_RELAXED, __HIP_MEMORY_SCOPE_AGENT);
    __hip_atomic_store((unsigned*)h1b[0] + i2, v1, __ATOMIC_RELAXED, __HIP_MEMORY_SCOPE_AGENT);
  }

  unsigned barno = 0;
  gridbar(bar, ++barno, wg);

  float c0r[8], c1r[8];
  #pragma unroll
  for (int q = 0; q < 8; ++q){ c0r[q] = 0.f; c1r[q] = 0.f; }

  int p = 0;
  for (int s = 1; s < T; ++s){
    const u16* h0p = h0b[p]; u16* h0n = h0b[p ^ 1];
    const u16* h1p = h1b[p]; u16* h1n = h1b[p ^ 1];
    // phase 1: gates0 = h1_prev@Weff^T + h0_prev@Whh0^T (+ out(s-1) on w<2)
    lstm_phase(wsmem, 0, h1p, h0p, s_b0, h0n, c0r, wg, w, lane);
    if (w < 2) out_tile(h1p, wsmem + WLOFF, blin, dout, T - s, wg, w, lane);
    gridbar(bar, ++barno, wg);
    // phase 2: gates1 = h0_new@Wih1^T + h1_prev@Whh1^T
    lstm_phase(wsmem, W1OFF, h0n, h1p, s_b1, h1n, c1r, wg, w, lane);
    gridbar(bar, ++barno, wg);
    p ^= 1;
  }
  if (w < 2) out_tile(h1b[p], wsmem + WLOFF, blin, dout, 0, wg, w, lane);
}

extern "C" void kernel_launch(void* const* d_in, const int* in_sizes, int n_in,
                              void* d_out, int out_size, void* d_ws, size_t ws_size,
                              hipStream_t stream) {
  const float* initial_hidden = (const float*)d_in[0];
  const float* Wih0 = (const float*)d_in[1];
  const float* Whh0 = (const float*)d_in[2];
  const float* bih0 = (const float*)d_in[3];
  const float* bhh0 = (const float*)d_in[4];
  const float* Wih1 = (const float*)d_in[5];
  const float* Whh1 = (const float*)d_in[6];
  const float* bih1 = (const float*)d_in[7];
  const float* bhh1 = (const float*)d_in[8];
  const float* Wlin = (const float*)d_in[9];
  const float* blin = (const float*)d_in[10];
  const int*   seqp = (const int*)d_in[11];

  hipMemsetAsync(d_ws, 0, 8192, stream);
  lstm_ae_kernel<<<dim3(NWG), dim3(NTHR), 0, stream>>>(
      initial_hidden, Wih0, Whh0, bih0, bhh0, Wih1, Whh1, bih1, bhh1,
      Wlin, blin, seqp, (float*)d_out, (char*)d_ws);
}

// Round 13
// 3075.197 us; speedup vs baseline: 5.0635x; 1.9587x over previous
//
#include <hip/hip_runtime.h>
#include <hip/hip_bf16.h>

#define NWG  256
#define NTHR 512

typedef __attribute__((ext_vector_type(8))) short bf16x8;
typedef __attribute__((ext_vector_type(4))) float f32x4;
typedef unsigned short u16;

__device__ __forceinline__ float sigm(float x){ return 1.f/(1.f+__expf(-x)); }
__device__ __forceinline__ float tanhf_(float x){ return 1.f - 2.f/(1.f+__expf(2.f*x)); }
__device__ __forceinline__ u16 f2bf(float x){
  union { float f; unsigned u; } v; v.f = x;
  return (u16)((v.u + 0x7fffu + ((v.u >> 16) & 1u)) >> 16);
}
__device__ __forceinline__ bf16x8 load8cvt(const float* p){
  f32x4 x0 = *(const f32x4*)p;
  f32x4 x1 = *(const f32x4*)(p + 4);
  union { u16 h[8]; bf16x8 v; } u;
  #pragma unroll
  for (int e = 0; e < 4; ++e){ u.h[e] = f2bf(x0[e]); u.h[4+e] = f2bf(x1[e]); }
  return u.v;
}

// ---- LLC-direct primitives (R11-validated): plain sc0 sc1 dwordx4 loads,
// early-clobber outputs, memory clobber; counted waits + sched_barrier.
__device__ __forceinline__ void llc_load16(bf16x8 (&A)[16], const u16* p){
  asm volatile(
    "global_load_dwordx4 %0, %16, off sc0 sc1\n\t"
    "global_load_dwordx4 %1, %16, off offset:64 sc0 sc1\n\t"
    "global_load_dwordx4 %2, %16, off offset:128 sc0 sc1\n\t"
    "global_load_dwordx4 %3, %16, off offset:192 sc0 sc1\n\t"
    "global_load_dwordx4 %4, %16, off offset:256 sc0 sc1\n\t"
    "global_load_dwordx4 %5, %16, off offset:320 sc0 sc1\n\t"
    "global_load_dwordx4 %6, %16, off offset:384 sc0 sc1\n\t"
    "global_load_dwordx4 %7, %16, off offset:448 sc0 sc1\n\t"
    "global_load_dwordx4 %8, %16, off offset:512 sc0 sc1\n\t"
    "global_load_dwordx4 %9, %16, off offset:576 sc0 sc1\n\t"
    "global_load_dwordx4 %10, %16, off offset:640 sc0 sc1\n\t"
    "global_load_dwordx4 %11, %16, off offset:704 sc0 sc1\n\t"
    "global_load_dwordx4 %12, %16, off offset:768 sc0 sc1\n\t"
    "global_load_dwordx4 %13, %16, off offset:832 sc0 sc1\n\t"
    "global_load_dwordx4 %14, %16, off offset:896 sc0 sc1\n\t"
    "global_load_dwordx4 %15, %16, off offset:960 sc0 sc1"
    : "=&v"(A[0]),"=&v"(A[1]),"=&v"(A[2]),"=&v"(A[3]),
      "=&v"(A[4]),"=&v"(A[5]),"=&v"(A[6]),"=&v"(A[7]),
      "=&v"(A[8]),"=&v"(A[9]),"=&v"(A[10]),"=&v"(A[11]),
      "=&v"(A[12]),"=&v"(A[13]),"=&v"(A[14]),"=&v"(A[15])
    : "v"(p) : "memory");
}
__device__ __forceinline__ void llc_wait0(){
  asm volatile("s_waitcnt vmcnt(0)" ::: "memory");
  __builtin_amdgcn_sched_barrier(0);
}

// One-time full-fence global barrier (256 WGs): publishes plain-stored ws
// data (Weff, biases). R4/R8-validated structure.
__device__ __forceinline__ void gridbar_full(unsigned* flags, unsigned barno, int b){
  __syncthreads();
  if (threadIdx.x == 0){
    __builtin_amdgcn_fence(__ATOMIC_RELEASE, "agent");
    __hip_atomic_store(&flags[b*16], barno, __ATOMIC_RELAXED, __HIP_MEMORY_SCOPE_AGENT);
  }
  if (threadIdx.x < NWG){
    const unsigned* f = &flags[threadIdx.x*16];
    while (__hip_atomic_load(f, __ATOMIC_RELAXED, __HIP_MEMORY_SCOPE_AGENT) < barno)
      __builtin_amdgcn_s_sleep(2);
    __builtin_amdgcn_fence(__ATOMIC_ACQUIRE, "agent");
  }
  __syncthreads();
}

// Fence-free intra-group barrier (32 WGs), R11-validated protocol: h moved
// via sc1 atomics/loads; __syncthreads drains vmcnt before the flag store.
__device__ __forceinline__ void gbar(unsigned* flags, unsigned barno, int b, int g){
  __syncthreads();
  if (threadIdx.x == 0)
    __hip_atomic_store(&flags[b*16], barno, __ATOMIC_RELAXED, __HIP_MEMORY_SCOPE_AGENT);
  if (threadIdx.x < 32){
    const unsigned* f = &flags[(g*32 + threadIdx.x)*16];
    while (__hip_atomic_load(f, __ATOMIC_RELAXED, __HIP_MEMORY_SCOPE_AGENT) < barno)
      __builtin_amdgcn_s_sleep(2);
  }
  __syncthreads();
}

// acc += h[16 rows x 512] @ bw^T (K=512); A via LLC-direct loads.
__device__ __forceinline__ void gemm16(f32x4& acc, const u16* h,
                                       const bf16x8 (&bw)[16], int lane){
  const int col = lane & 15, kg = lane >> 4;
  bf16x8 A[16];
  llc_load16(A, h + col*512 + kg*8);
  llc_wait0();
  #pragma unroll
  for (int ks = 0; ks < 16; ++ks)
    acc = __builtin_amdgcn_mfma_f32_16x16x32_bf16(A[ks], bw[ks], acc, 0, 0, 0);
}

// LSTM cell epilogue (validated shuffle structure), M=16, N=16.
__device__ __forceinline__ void epi(f32x4 acc, const float (&b4)[4], float* cr,
                                    u16* dst, int ubase, int lane){
  const int col = lane & 15, kg = lane >> 4;
  #pragma unroll
  for (int r = 0; r < 4; ++r){
    float v  = acc[r];
    float vf = __shfl(v, (lane + 4) & 63);
    float vg = __shfl(v, (lane + 8) & 63);
    float vo = __shfl(v, (lane + 12) & 63);
    float vi = v + b4[0];
    vf += b4[1]; vg += b4[2]; vo += b4[3];
    float cn = sigm(vf)*cr[r] + sigm(vi)*tanhf_(vg);
    if (col < 4) cr[r] = cn;
    float hv = sigm(vo)*tanhf_(cn);
    unsigned hb = f2bf(hv);
    unsigned hp = __shfl(hb, lane ^ 1);
    if (col < 4 && !(col & 1))
      __hip_atomic_store((unsigned*)(dst + (kg*4 + r)*512 + ubase + col),
                         hb | (hp << 16), __ATOMIC_RELAXED, __HIP_MEMORY_SCOPE_AGENT);
  }
}

// out tile: group's 16 batch rows x 16 out cols, K=512; B from LDS (padded).
__device__ __forceinline__ void out_tile(const u16* h1p, const u16* swl,
    const float* blin, float* dout, int slotOut, int g, int sWG, int lane){
  const int col = lane & 15, kg = lane >> 4;
  bf16x8 A[16];
  llc_load16(A, h1p + col*512 + kg*8);
  llc_wait0();
  f32x4 acc = {0.f,0.f,0.f,0.f};
  #pragma unroll
  for (int ks = 0; ks < 16; ++ks){
    bf16x8 bfr = *(const bf16x8*)(swl + col*528 + ks*32 + kg*8);
    acc = __builtin_amdgcn_mfma_f32_16x16x32_bf16(A[ks], bfr, acc, 0, 0, 0);
  }
  const float bl = blin[sWG*16 + col];
  #pragma unroll
  for (int r = 0; r < 4; ++r)
    dout[(size_t)slotOut*32768 + (g*16 + kg*4 + r)*256 + sWG*16 + col] = acc[r] + bl;
}

__global__ __launch_bounds__(NTHR) void lstm_ae_kernel(
  const float* __restrict__ initial_hidden,
  const float* __restrict__ Wih0, const float* __restrict__ Whh0,
  const float* __restrict__ bih0, const float* __restrict__ bhh0,
  const float* __restrict__ Wih1, const float* __restrict__ Whh1,
  const float* __restrict__ bih1, const float* __restrict__ bhh1,
  const float* __restrict__ Wlin, const float* __restrict__ blin,
  const int* __restrict__ seqp,
  float* __restrict__ dout, char* __restrict__ ws)
{
  __shared__ float sw[8*256];      // 8 Wih0 rows (f32), phase 1
  __shared__ u16 swl[16*528];      // layer-1 WGs: padded Wlin slice
  const int tid = threadIdx.x, b = blockIdx.x;
  const int g = b >> 5, slot = b & 31;
  const int w = tid >> 6, lane = tid & 63;
  const int col = lane & 15, kg = lane >> 4, c4 = col & 3;
  const int layer = slot >> 4, sWG = slot & 15;
  const int ubase = (sWG*8 + w)*4;             // this wave's 4 hidden units
  const int T = seqp[0];

  unsigned* flags = (unsigned*)ws;                       // 256 x 64B
  u16* hb = (u16*)(ws + 32768) + g*32768;                // 64KB per group
  u16* h0b[2] = { hb,         hb + 8192  };
  u16* h1b[2] = { hb + 16384, hb + 24576 };
  u16*   wsWeff = (u16*)(ws + (1u << 20));               // [2048][512] bf16
  float* b0e    = (float*)(ws + (3u << 20));             // [2048] f32
  float* b1e    = (float*)(ws + (3u << 20) + 8192);      // [2048] f32

  // ---------------- phase 1: cooperative Weff/bias prep (R9-validated math)
  // WG b owns Weff rows [b*8, b*8+8).
  for (int it = tid; it < 8*256; it += NTHR) sw[it] = Wih0[b*2048 + it];
  __syncthreads();
  {
    const int cc = tid;
    float a8[8];
    #pragma unroll
    for (int rr = 0; rr < 8; ++rr) a8[rr] = 0.f;
    for (int d = 0; d < 256; ++d){
      const float wl = Wlin[d*512 + cc];
      #pragma unroll
      for (int rr = 0; rr < 8; ++rr) a8[rr] += sw[rr*256 + d] * wl;
    }
    #pragma unroll
    for (int rr = 0; rr < 8; ++rr) wsWeff[(size_t)(b*8 + rr)*512 + cc] = f2bf(a8[rr]);
  }
  if (tid < 8){
    const int r = b*8 + tid;
    float s = bih0[r] + bhh0[r];
    for (int d = 0; d < 256; ++d) s += sw[tid*256 + d] * blin[d];
    b0e[r] = s;
  } else if (tid < 16){
    const int r = b*8 + (tid - 8);
    b1e[r] = bih1[r] + bhh1[r];
  }
  // h(0) init: slot 0 of each group, sc1 atomic u32 stores
  if (slot == 0){
    for (int i2 = tid; i2 < 4096; i2 += NTHR){
      const int row = i2 >> 8, ci = i2 & 255;
      const size_t src = (size_t)(g*16 + row)*512 + 2*ci;
      unsigned v0 = (unsigned)f2bf(initial_hidden[65536 + src])
                  | ((unsigned)f2bf(initial_hidden[65536 + src + 1]) << 16);
      unsigned v1 = (unsigned)f2bf(initial_hidden[src])
                  | ((unsigned)f2bf(initial_hidden[src + 1]) << 16);
      __hip_atomic_store((unsigned*)h0b[0] + i2, v0, __ATOMIC_RELAXED, __HIP_MEMORY_SCOPE_AGENT);
      __hip_atomic_store((unsigned*)h1b[0] + i2, v1, __ATOMIC_RELAXED, __HIP_MEMORY_SCOPE_AGENT);
    }
  }
  // layer-1 WGs: Wlin slice (cols sWG*16..+16) into padded LDS
  if (layer == 1){
    for (int it = tid; it < 16*512; it += NTHR){
      const int row = it >> 9, kk = it & 511;
      swl[row*528 + kk] = f2bf(Wlin[(size_t)(sWG*16 + row)*512 + kk]);
    }
  }

  unsigned barno = 1;
  gridbar_full(flags, barno, b);   // publish Weff, biases, h(0)

  // ---------------- phase 2: weight fragments -> registers (128 VGPR/wave)
  const int growL = (col >> 2)*512 + ubase + c4;   // this lane's gate row
  bf16x8 bwd[16], bwp[16];
  if (layer == 0){
    #pragma unroll
    for (int ks = 0; ks < 16; ++ks)
      bwd[ks] = *(const bf16x8*)(wsWeff + (size_t)growL*512 + ks*32 + kg*8);
    #pragma unroll
    for (int ks = 0; ks < 16; ++ks)
      bwp[ks] = load8cvt(Whh0 + (size_t)growL*512 + ks*32 + kg*8);
  } else {
    #pragma unroll
    for (int ks = 0; ks < 16; ++ks)
      bwd[ks] = load8cvt(Wih1 + (size_t)growL*512 + ks*32 + kg*8);
    #pragma unroll
    for (int ks = 0; ks < 16; ++ks)
      bwp[ks] = load8cvt(Whh1 + (size_t)growL*512 + ks*32 + kg*8);
  }
  #pragma unroll
  for (int t = 0; t < 16; ++t) asm volatile("" : "+v"(bwd[t]), "+v"(bwp[t]));
  const float* be = layer ? b1e : b0e;
  float b4[4];
  #pragma unroll
  for (int gg = 0; gg < 4; ++gg) b4[gg] = be[gg*512 + ubase + c4];

  f32x4 accP = {0.f,0.f,0.f,0.f};
  float cr[4] = {0.f,0.f,0.f,0.f};
  if (layer == 0) gemm16(accP, h0b[0], bwp, lane);   // Whh0·h0(0)

  // ---------------- sequential loop: 2 intra-group barriers per step ------
  int p = 0;
  for (int s = 1; s < T; ++s){
    // window A: L0 finishes h0(s) = Weff·h1(s-1) + [pre]; L1 prefetches
    // Whh1·h1(s-1); L1 wave 0 emits out(s-1).
    if (layer == 0){
      f32x4 a = accP;
      gemm16(a, h1b[p], bwd, lane);
      epi(a, b4, cr, h0b[p ^ 1], ubase, lane);
    } else {
      gemm16(accP, h1b[p], bwp, lane);
      if (w == 0) out_tile(h1b[p], swl, blin, dout, T - s, g, sWG, lane);
    }
    gbar(flags, ++barno, b, g);
    // window B: L1 finishes h1(s) = Wih1·h0(s) + [pre]; L0 prefetches
    // Whh0·h0(s) for step s+1.
    if (layer == 1){
      f32x4 a = accP;
      gemm16(a, h0b[p ^ 1], bwd, lane);
      epi(a, b4, cr, h1b[p ^ 1], ubase, lane);
      accP = (f32x4){0.f,0.f,0.f,0.f};
    } else {
      accP = (f32x4){0.f,0.f,0.f,0.f};
      gemm16(accP, h0b[p ^ 1], bwp, lane);
    }
    gbar(flags, ++barno, b, g);
    p ^= 1;
  }
  if (layer == 1 && w == 0) out_tile(h1b[p], swl, blin, dout, 0, g, sWG, lane);
}

extern "C" void kernel_launch(void* const* d_in, const int* in_sizes, int n_in,
                              void* d_out, int out_size, void* d_ws, size_t ws_size,
                              hipStream_t stream) {
  const float* initial_hidden = (const float*)d_in[0];
  const float* Wih0 = (const float*)d_in[1];
  const float* Whh0 = (const float*)d_in[2];
  const float* bih0 = (const float*)d_in[3];
  const float* bhh0 = (const float*)d_in[4];
  const float* Wih1 = (const float*)d_in[5];
  const float* Whh1 = (const float*)d_in[6];
  const float* bih1 = (const float*)d_in[7];
  const float* bhh1 = (const float*)d_in[8];
  const float* Wlin = (const float*)d_in[9];
  const float* blin = (const float*)d_in[10];
  const int*   seqp = (const int*)d_in[11];

  hipMemsetAsync(d_ws, 0, 16384, stream);   // flag lines
  lstm_ae_kernel<<<dim3(NWG), dim3(NTHR), 0, stream>>>(
      initial_hidden, Wih0, Whh0, bih0, bhh0, Wih1, Whh1, bih1, bhh1,
      Wlin, blin, seqp, (float*)d_out, (char*)d_ws);
}

// Round 14
// 1861.253 us; speedup vs baseline: 8.3660x; 1.6522x over previous
//
#include <hip/hip_runtime.h>
#include <hip/hip_bf16.h>

#define NWG  256
#define NTHR 512

typedef __attribute__((ext_vector_type(8))) short bf16x8;
typedef __attribute__((ext_vector_type(4))) float f32x4;
typedef unsigned short u16;

__device__ __forceinline__ float sigm(float x){ return 1.f/(1.f+__expf(-x)); }
__device__ __forceinline__ float tanhf_(float x){ return 1.f - 2.f/(1.f+__expf(2.f*x)); }
__device__ __forceinline__ u16 f2bf(float x){
  union { float f; unsigned u; } v; v.f = x;
  return (u16)((v.u + 0x7fffu + ((v.u >> 16) & 1u)) >> 16);
}
__device__ __forceinline__ bf16x8 load8cvt(const float* p){
  f32x4 x0 = *(const f32x4*)p;
  f32x4 x1 = *(const f32x4*)(p + 4);
  union { u16 h[8]; bf16x8 v; } u;
  #pragma unroll
  for (int e = 0; e < 4; ++e){ u.h[e] = f2bf(x0[e]); u.h[4+e] = f2bf(x1[e]); }
  return u.v;
}

// ---- LLC-direct 16-frag load (R11-validated): epilogue A-reads.
__device__ __forceinline__ void llc_load16(bf16x8 (&A)[16], const u16* p){
  asm volatile(
    "global_load_dwordx4 %0, %16, off sc0 sc1\n\t"
    "global_load_dwordx4 %1, %16, off offset:64 sc0 sc1\n\t"
    "global_load_dwordx4 %2, %16, off offset:128 sc0 sc1\n\t"
    "global_load_dwordx4 %3, %16, off offset:192 sc0 sc1\n\t"
    "global_load_dwordx4 %4, %16, off offset:256 sc0 sc1\n\t"
    "global_load_dwordx4 %5, %16, off offset:320 sc0 sc1\n\t"
    "global_load_dwordx4 %6, %16, off offset:384 sc0 sc1\n\t"
    "global_load_dwordx4 %7, %16, off offset:448 sc0 sc1\n\t"
    "global_load_dwordx4 %8, %16, off offset:512 sc0 sc1\n\t"
    "global_load_dwordx4 %9, %16, off offset:576 sc0 sc1\n\t"
    "global_load_dwordx4 %10, %16, off offset:640 sc0 sc1\n\t"
    "global_load_dwordx4 %11, %16, off offset:704 sc0 sc1\n\t"
    "global_load_dwordx4 %12, %16, off offset:768 sc0 sc1\n\t"
    "global_load_dwordx4 %13, %16, off offset:832 sc0 sc1\n\t"
    "global_load_dwordx4 %14, %16, off offset:896 sc0 sc1\n\t"
    "global_load_dwordx4 %15, %16, off offset:960 sc0 sc1"
    : "=&v"(A[0]),"=&v"(A[1]),"=&v"(A[2]),"=&v"(A[3]),
      "=&v"(A[4]),"=&v"(A[5]),"=&v"(A[6]),"=&v"(A[7]),
      "=&v"(A[8]),"=&v"(A[9]),"=&v"(A[10]),"=&v"(A[11]),
      "=&v"(A[12]),"=&v"(A[13]),"=&v"(A[14]),"=&v"(A[15])
    : "v"(p) : "memory");
}
__device__ __forceinline__ void llc_wait0(){
  asm volatile("s_waitcnt vmcnt(0)" ::: "memory");
  __builtin_amdgcn_sched_barrier(0);
}

// Cooperative stage: 16 rows x 512 bf16 (16KB) LLC -> LDS, XOR-swizzled.
// 512 threads x 2 chunks of 16B. Caller guarantees no wave is still reading
// the LDS buffer (always invoked right after a barrier's trailing sync).
__device__ __forceinline__ void stage_h(char* sAb, const u16* h, int tid){
  bf16x8 v0, v1;
  const u16* p0 = h + tid*8;
  const u16* p1 = h + 4096 + tid*8;
  asm volatile(
    "global_load_dwordx4 %0, %2, off sc0 sc1\n\t"
    "global_load_dwordx4 %1, %3, off sc0 sc1"
    : "=&v"(v0), "=&v"(v1) : "v"(p0), "v"(p1) : "memory");
  asm volatile("s_waitcnt vmcnt(0)" ::: "memory");
  __builtin_amdgcn_sched_barrier(0);
  const int c0 = tid, c1 = tid + 512;
  const int r0 = c0 >> 6, b0 = (c0 & 63) << 4;
  const int r1 = c1 >> 6, b1 = (c1 & 63) << 4;
  *(bf16x8*)(sAb + r0*1024 + (b0 ^ ((r0 & 7) << 4))) = v0;
  *(bf16x8*)(sAb + r1*1024 + (b1 ^ ((r1 & 7) << 4))) = v1;
  __syncthreads();
}

// One-time full-fence global barrier (publishes plain-stored ws data).
__device__ __forceinline__ void gridbar_full(unsigned* flags, unsigned barno, int b){
  __syncthreads();
  if (threadIdx.x == 0){
    __builtin_amdgcn_fence(__ATOMIC_RELEASE, "agent");
    __hip_atomic_store(&flags[b*16], barno, __ATOMIC_RELAXED, __HIP_MEMORY_SCOPE_AGENT);
  }
  if (threadIdx.x < NWG){
    const unsigned* f = &flags[threadIdx.x*16];
    while (__hip_atomic_load(f, __ATOMIC_RELAXED, __HIP_MEMORY_SCOPE_AGENT) < barno)
      __builtin_amdgcn_s_sleep(2);
    __builtin_amdgcn_fence(__ATOMIC_ACQUIRE, "agent");
  }
  __syncthreads();
}
// Fence-free 256-WG barrier (sc1 data only): before the output epilogue.
__device__ __forceinline__ void gridbar_wide(unsigned* flags, unsigned barno, int b){
  __syncthreads();
  if (threadIdx.x == 0)
    __hip_atomic_store(&flags[b*16], barno, __ATOMIC_RELAXED, __HIP_MEMORY_SCOPE_AGENT);
  if (threadIdx.x < NWG){
    const unsigned* f = &flags[threadIdx.x*16];
    while (__hip_atomic_load(f, __ATOMIC_RELAXED, __HIP_MEMORY_SCOPE_AGENT) < barno)
      __builtin_amdgcn_s_sleep(2);
  }
  __syncthreads();
}
// Fence-free intra-group barrier (32 WGs), R11/R13-validated protocol.
__device__ __forceinline__ void gbar(unsigned* flags, unsigned barno, int b, int g){
  __syncthreads();
  if (threadIdx.x == 0)
    __hip_atomic_store(&flags[b*16], barno, __ATOMIC_RELAXED, __HIP_MEMORY_SCOPE_AGENT);
  if (threadIdx.x < 32){
    const unsigned* f = &flags[(g*32 + threadIdx.x)*16];
    while (__hip_atomic_load(f, __ATOMIC_RELAXED, __HIP_MEMORY_SCOPE_AGENT) < barno)
      __builtin_amdgcn_s_sleep(2);
  }
  __syncthreads();
}

// acc += A_lds[16x512] @ bw^T (K=512); A from swizzled LDS.
__device__ __forceinline__ void gemm16_lds(f32x4& acc, const char* sAb,
                                           const bf16x8 (&bw)[16], int lane){
  const int col = lane & 15, kg = lane >> 4;
  const char* arow = sAb + col*1024;
  const int xr = (col & 7) << 4;
  #pragma unroll
  for (int ks = 0; ks < 16; ++ks){
    bf16x8 A = *(const bf16x8*)(arow + ((ks*64 + kg*16) ^ xr));
    acc = __builtin_amdgcn_mfma_f32_16x16x32_bf16(A, bw[ks], acc, 0, 0, 0);
  }
}

// LSTM cell epilogue (validated shuffle structure), M=16, N=16; sc1 h-stores.
__device__ __forceinline__ void epi(f32x4 acc, const float (&b4)[4], float* cr,
                                    u16* dst, int ubase, int lane){
  const int col = lane & 15, kg = lane >> 4;
  #pragma unroll
  for (int r = 0; r < 4; ++r){
    float v  = acc[r];
    float vf = __shfl(v, (lane + 4) & 63);
    float vg = __shfl(v, (lane + 8) & 63);
    float vo = __shfl(v, (lane + 12) & 63);
    float vi = v + b4[0];
    vf += b4[1]; vg += b4[2]; vo += b4[3];
    float cn = sigm(vf)*cr[r] + sigm(vi)*tanhf_(vg);
    if (col < 4) cr[r] = cn;
    float hv = sigm(vo)*tanhf_(cn);
    unsigned hb = f2bf(hv);
    unsigned hp = __shfl(hb, lane ^ 1);
    if (col < 4 && !(col & 1))
      __hip_atomic_store((unsigned*)(dst + (kg*4 + r)*512 + ubase + col),
                         hb | (hp << 16), __ATOMIC_RELAXED, __HIP_MEMORY_SCOPE_AGENT);
  }
}

__global__ __launch_bounds__(NTHR) void lstm_ae_kernel(
  const float* __restrict__ initial_hidden,
  const float* __restrict__ Wih0, const float* __restrict__ Whh0,
  const float* __restrict__ bih0, const float* __restrict__ bhh0,
  const float* __restrict__ Wih1, const float* __restrict__ Whh1,
  const float* __restrict__ bih1, const float* __restrict__ bhh1,
  const float* __restrict__ Wlin, const float* __restrict__ blin,
  const int* __restrict__ seqp,
  float* __restrict__ dout, char* __restrict__ ws)
{
  __shared__ float sw[8*256];                  // prologue scratch (8 KB)
  __shared__ __align__(16) char sAb[16384];    // staged A tile (16 KB)
  const int tid = threadIdx.x, b = blockIdx.x;
  const int g = b >> 5, slot = b & 31;
  const int w = tid >> 6, lane = tid & 63;
  const int col = lane & 15, kg = lane >> 4, c4 = col & 3;
  const int layer = slot >> 4, sWG = slot & 15;
  const int ubase = (sWG*8 + w)*4;             // this wave's 4 hidden units
  const int T = seqp[0];

  unsigned* flags = (unsigned*)ws;                       // 256 x 64B
  u16* h0base = (u16*)(ws + 32768) + g*16384;            // 32KB per group
  u16* h0b[2] = { h0base, h0base + 8192 };
  u16*   wsWeff = (u16*)(ws + (1u << 20));               // [2048][512] bf16
  float* b0e    = (float*)(ws + (3u << 20));             // [2048] f32
  float* b1e    = (float*)(ws + (3u << 20) + 8192);      // [2048] f32
  u16*   wlinb  = (u16*)(ws + (3u << 20) + 65536);       // [256][512] bf16
  u16*   hist   = (u16*)dout;                            // slot j: 65536 u16

  // ---------------- phase 1: cooperative Weff/bias/wlinb prep -------------
  for (int it = tid; it < 8*256; it += NTHR) sw[it] = Wih0[b*2048 + it];
  __syncthreads();
  {
    const int cc = tid;
    float a8[8];
    #pragma unroll
    for (int rr = 0; rr < 8; ++rr) a8[rr] = 0.f;
    for (int d = 0; d < 256; ++d){
      const float wl = Wlin[d*512 + cc];
      #pragma unroll
      for (int rr = 0; rr < 8; ++rr) a8[rr] += sw[rr*256 + d] * wl;
    }
    #pragma unroll
    for (int rr = 0; rr < 8; ++rr) wsWeff[(size_t)(b*8 + rr)*512 + cc] = f2bf(a8[rr]);
  }
  if (tid < 8){
    const int r = b*8 + tid;
    float s = bih0[r] + bhh0[r];
    for (int d = 0; d < 256; ++d) s += sw[tid*256 + d] * blin[d];
    b0e[r] = s;
  } else if (tid < 16){
    const int r = b*8 + (tid - 8);
    b1e[r] = bih1[r] + bhh1[r];
  }
  wlinb[b*512 + tid] = f2bf(Wlin[b*512 + tid]);   // 512 elems per WG
  // h(0) init by slot-0 WG of each group: h0 -> ws, h1 -> hist slot T-1
  if (slot == 0){
    unsigned* h1d = (unsigned*)(hist + (size_t)(T - 1)*65536 + g*8192);
    for (int i2 = tid; i2 < 4096; i2 += NTHR){
      const int row = i2 >> 8, ci = i2 & 255;
      const size_t src = (size_t)(g*16 + row)*512 + 2*ci;
      unsigned v0 = (unsigned)f2bf(initial_hidden[65536 + src])
                  | ((unsigned)f2bf(initial_hidden[65536 + src + 1]) << 16);
      unsigned v1 = (unsigned)f2bf(initial_hidden[src])
                  | ((unsigned)f2bf(initial_hidden[src + 1]) << 16);
      __hip_atomic_store((unsigned*)h0b[0] + i2, v0, __ATOMIC_RELAXED, __HIP_MEMORY_SCOPE_AGENT);
      __hip_atomic_store(h1d + i2, v1, __ATOMIC_RELAXED, __HIP_MEMORY_SCOPE_AGENT);
    }
  }

  unsigned barno = 1;
  gridbar_full(flags, barno, b);   // publish Weff, biases, wlinb, h(0)

  // ---------------- phase 2: weight fragments -> registers ----------------
  const int growL = (col >> 2)*512 + ubase + c4;   // this lane's gate row
  bf16x8 bwd[16], bwp[16];
  if (layer == 0){
    #pragma unroll
    for (int ks = 0; ks < 16; ++ks)
      bwd[ks] = *(const bf16x8*)(wsWeff + (size_t)growL*512 + ks*32 + kg*8);
    #pragma unroll
    for (int ks = 0; ks < 16; ++ks)
      bwp[ks] = load8cvt(Whh0 + (size_t)growL*512 + ks*32 + kg*8);
  } else {
    #pragma unroll
    for (int ks = 0; ks < 16; ++ks)
      bwd[ks] = load8cvt(Wih1 + (size_t)growL*512 + ks*32 + kg*8);
    #pragma unroll
    for (int ks = 0; ks < 16; ++ks)
      bwp[ks] = load8cvt(Whh1 + (size_t)growL*512 + ks*32 + kg*8);
  }
  #pragma unroll
  for (int t = 0; t < 16; ++t) asm volatile("" : "+v"(bwd[t]), "+v"(bwp[t]));
  const float* be = layer ? b1e : b0e;
  float b4[4];
  #pragma unroll
  for (int gg = 0; gg < 4; ++gg) b4[gg] = be[gg*512 + ubase + c4];

  f32x4 accP = {0.f,0.f,0.f,0.f};
  float cr[4] = {0.f,0.f,0.f,0.f};
  // pre-loop: stage h0(0), layer-0 prefetches Whh0·h0(0)
  stage_h(sAb, h0b[0], tid);
  if (layer == 0) gemm16_lds(accP, sAb, bwp, lane);
  __syncthreads();   // all waves done with sAb before first loop stage

  // ---------------- sequential loop: 2 intra-group barriers per step ------
  int p = 0;
  for (int s = 1; s < T; ++s){
    // window A: shared A = h1(s-1) (hist). L0 finishes h0(s); L1 prefetches.
    stage_h(sAb, hist + (size_t)(T - s)*65536 + g*8192, tid);
    if (layer == 0){
      f32x4 a = accP;
      gemm16_lds(a, sAb, bwd, lane);
      epi(a, b4, cr, h0b[p ^ 1], ubase, lane);
    } else {
      gemm16_lds(accP, sAb, bwp, lane);
    }
    gbar(flags, ++barno, b, g);
    // window B: shared A = h0(s). L1 finishes h1(s) -> hist; L0 prefetches.
    stage_h(sAb, h0b[p ^ 1], tid);
    if (layer == 1){
      f32x4 a = accP;
      gemm16_lds(a, sAb, bwd, lane);
      epi(a, b4, cr, hist + (size_t)(T - 1 - s)*65536 + g*8192, ubase, lane);
      accP = (f32x4){0.f,0.f,0.f,0.f};
    } else {
      accP = (f32x4){0.f,0.f,0.f,0.f};
      gemm16_lds(accP, sAb, bwp, lane);
    }
    gbar(flags, ++barno, b, g);
    p ^= 1;
  }

  // wait for ALL groups' hist slots, then output epilogue (R9-validated
  // in-place pattern): out[b] = hist[b] @ Wlin^T + blin.
  gridbar_wide(flags, ++barno, b);
  if (b < T){
    const u16* hsl = hist + (size_t)b*65536;
    float* osl = dout + (size_t)b*32768;
    bf16x8 A[16];
    llc_load16(A, hsl + (w*16 + col)*512 + kg*8);
    llc_wait0();                      // all reads done before in-place writes
    #pragma unroll
    for (int nb = 0; nb < 16; ++nb){
      f32x4 acc = {0.f,0.f,0.f,0.f};
      const u16* bp = wlinb + (size_t)(nb*16 + col)*512 + kg*8;
      #pragma unroll
      for (int ks = 0; ks < 16; ++ks){
        bf16x8 bfr = *(const bf16x8*)(bp + ks*32);
        acc = __builtin_amdgcn_mfma_f32_16x16x32_bf16(A[ks], bfr, acc, 0, 0, 0);
      }
      const float bl = blin[nb*16 + col];
      #pragma unroll
      for (int r = 0; r < 4; ++r)
        osl[(w*16 + kg*4 + r)*256 + nb*16 + col] = acc[r] + bl;
    }
  }
}

extern "C" void kernel_launch(void* const* d_in, const int* in_sizes, int n_in,
                              void* d_out, int out_size, void* d_ws, size_t ws_size,
                              hipStream_t stream) {
  const float* initial_hidden = (const float*)d_in[0];
  const float* Wih0 = (const float*)d_in[1];
  const float* Whh0 = (const float*)d_in[2];
  const float* bih0 = (const float*)d_in[3];
  const float* bhh0 = (const float*)d_in[4];
  const float* Wih1 = (const float*)d_in[5];
  const float* Whh1 = (const float*)d_in[6];
  const float* bih1 = (const float*)d_in[7];
  const float* bhh1 = (const float*)d_in[8];
  const float* Wlin = (const float*)d_in[9];
  const float* blin = (const float*)d_in[10];
  const int*   seqp = (const int*)d_in[11];

  hipMemsetAsync(d_ws, 0, 16384, stream);   // flag lines
  lstm_ae_kernel<<<dim3(NWG), dim3(NTHR), 0, stream>>>(
      initial_hidden, Wih0, Whh0, bih0, bhh0, Wih1, Whh1, bih1, bhh1,
      Wlin, blin, seqp, (float*)d_out, (char*)d_ws);
}